// Round 1
// baseline (679.918 us; speedup 1.0000x reference)
//
#include <hip/hip_runtime.h>

// ---------------- problem constants ----------------
constexpr int KC    = 4096;      // NUM_EMBEDDINGS
constexpr int DIM   = 64;        // EMBEDDING_DIM
constexpr int NROWS = 73728;     // 128*24*1536/64
constexpr int NELEM = 4718592;   // 128*24*1536

// ---------------- output layout (floats) ----------------
constexpr size_t OUT_LOSS  = 0;                               // 1
constexpr size_t OUT_ZQ    = 1;                               // NELEM
constexpr size_t OUT_CODES = 1 + (size_t)NELEM;               // NROWS
constexpr size_t OUT_EMB   = OUT_CODES + (size_t)NROWS;       // KC*DIM
constexpr size_t OUT_NCS   = OUT_EMB + (size_t)KC * DIM;      // KC
constexpr size_t OUT_NEW   = OUT_NCS + (size_t)KC;            // KC*DIM

// ---------------- workspace layout (bytes) ----------------
constexpr size_t WS_CODES  = 0;                                      // int[NROWS]
constexpr size_t WS_COUNTS = WS_CODES + sizeof(int) * (size_t)NROWS; // int[KC]
constexpr size_t WS_DW     = WS_COUNTS + sizeof(int) * (size_t)KC;   // float[KC*DIM]
constexpr size_t WS_E2     = WS_DW + sizeof(float) * (size_t)KC * DIM; // float[KC]
constexpr size_t WS_N      = WS_E2 + sizeof(float) * (size_t)KC;     // float[1]
constexpr size_t WS_LOSSD  = (WS_N + sizeof(float) + 7) & ~(size_t)7; // double[1]

// ---------------- kernel: per-code squared norms ----------------
__global__ void k_e2(const float* __restrict__ emb, float* __restrict__ e2) {
    int k = blockIdx.x * blockDim.x + threadIdx.x;
    if (k < KC) {
        const float* e = emb + (size_t)k * DIM;
        float s = 0.f;
        #pragma unroll
        for (int d = 0; d < DIM; ++d) s = fmaf(e[d], e[d], s);
        e2[k] = s;
    }
}

// ---------------- kernel: distance argmin + EMA scatter ----------------
// block: 256 threads as (tx in [0,16), ty in [0,16)); tile 64 rows x 64 codes,
// each thread owns a 4x4 (row,code) sub-tile, full d=64 per K-tile.
__global__ __launch_bounds__(256) void k_argmin(
        const float* __restrict__ z, const float* __restrict__ emb,
        const float* __restrict__ e2g,
        int* __restrict__ codes_i, float* __restrict__ codes_f,
        int* __restrict__ counts, float* __restrict__ dw) {
    __shared__ float zs[64][68];   // [row][d]   (stride 68 floats = 16B aligned)
    __shared__ float es[64][68];   // [d][code]  (transposed for b128-over-codes)
    __shared__ float z2s[64];
    __shared__ float e2s[64];

    const int tid = threadIdx.x;
    const int tx = tid & 15, ty = tid >> 4;
    const int tx4 = tx * 4, ty4 = ty * 4;
    const int rowBase = blockIdx.x * 64;

    // stage z tile (coalesced: consecutive lanes -> consecutive d)
    for (int idx = tid; idx < 64 * DIM; idx += 256) {
        int r = idx >> 6, d = idx & 63;
        zs[r][d] = z[(size_t)(rowBase + r) * DIM + d];
    }
    __syncthreads();
    if (tid < 64) {
        float s = 0.f;
        #pragma unroll
        for (int d = 0; d < DIM; ++d) s = fmaf(zs[tid][d], zs[tid][d], s);
        z2s[tid] = s;
    }

    float best[4];
    int   bestk[4];
    #pragma unroll
    for (int i = 0; i < 4; ++i) { best[i] = INFINITY; bestk[i] = 0; }

    for (int kt = 0; kt < KC; kt += 64) {
        __syncthreads();   // protect previous tile reads (and z2s on iter 0)
        for (int idx = tid; idx < 64 * DIM; idx += 256) {
            int kk = idx >> 6, d = idx & 63;
            es[d][kk] = emb[(size_t)(kt + kk) * DIM + d];
        }
        if (tid < 64) e2s[tid] = e2g[kt + tid];
        __syncthreads();

        float acc[4][4];
        #pragma unroll
        for (int i = 0; i < 4; ++i)
            #pragma unroll
            for (int j = 0; j < 4; ++j) acc[i][j] = 0.f;

        #pragma unroll
        for (int dd = 0; dd < DIM; dd += 4) {
            float4 eb0 = *(const float4*)&es[dd + 0][tx4];
            float4 eb1 = *(const float4*)&es[dd + 1][tx4];
            float4 eb2 = *(const float4*)&es[dd + 2][tx4];
            float4 eb3 = *(const float4*)&es[dd + 3][tx4];
            #pragma unroll
            for (int i = 0; i < 4; ++i) {
                float4 za = *(const float4*)&zs[ty4 + i][dd];
                acc[i][0] = fmaf(za.x, eb0.x, acc[i][0]);
                acc[i][1] = fmaf(za.x, eb0.y, acc[i][1]);
                acc[i][2] = fmaf(za.x, eb0.z, acc[i][2]);
                acc[i][3] = fmaf(za.x, eb0.w, acc[i][3]);
                acc[i][0] = fmaf(za.y, eb1.x, acc[i][0]);
                acc[i][1] = fmaf(za.y, eb1.y, acc[i][1]);
                acc[i][2] = fmaf(za.y, eb1.z, acc[i][2]);
                acc[i][3] = fmaf(za.y, eb1.w, acc[i][3]);
                acc[i][0] = fmaf(za.z, eb2.x, acc[i][0]);
                acc[i][1] = fmaf(za.z, eb2.y, acc[i][1]);
                acc[i][2] = fmaf(za.z, eb2.z, acc[i][2]);
                acc[i][3] = fmaf(za.z, eb2.w, acc[i][3]);
                acc[i][0] = fmaf(za.w, eb3.x, acc[i][0]);
                acc[i][1] = fmaf(za.w, eb3.y, acc[i][1]);
                acc[i][2] = fmaf(za.w, eb3.z, acc[i][2]);
                acc[i][3] = fmaf(za.w, eb3.w, acc[i][3]);
            }
        }

        // dist = (z2 + e2) - 2*g, fp32 semantics like the reference
        #pragma unroll
        for (int i = 0; i < 4; ++i) {
            float zz = z2s[ty4 + i];
            #pragma unroll
            for (int j = 0; j < 4; ++j) {
                float s = zz + e2s[tx4 + j];
                float dist = s - 2.0f * acc[i][j];
                int k = kt + tx4 + j;
                if (dist < best[i]) { best[i] = dist; bestk[i] = k; }
            }
        }
    }

    // reduce across the 16 tx-lanes sharing each row (contiguous 16 lanes)
    #pragma unroll
    for (int i = 0; i < 4; ++i) {
        float b = best[i];
        int   k = bestk[i];
        #pragma unroll
        for (int m = 1; m < 16; m <<= 1) {
            float ob = __shfl_xor(b, m, 64);
            int   ok = __shfl_xor(k, m, 64);
            if (ob < b || (ob == b && ok < k)) { b = ob; k = ok; }
        }
        int row = ty4 + i;
        int n = rowBase + row;
        if (tx == 0) {
            codes_i[n] = k;
            codes_f[n] = (float)k;
            atomicAdd(&counts[k], 1);
        }
        #pragma unroll
        for (int j = 0; j < 4; ++j)
            atomicAdd(&dw[(size_t)k * DIM + tx4 + j], zs[row][tx4 + j]);
    }
}

// ---------------- kernel: new_cluster_size + n ----------------
__global__ void k_cluster(const float* __restrict__ ema_cs,
                          const int* __restrict__ counts,
                          float* __restrict__ ncs_out, float* __restrict__ n_out) {
    __shared__ float red[256];
    int tid = threadIdx.x;
    float s = 0.f;
    for (int k = tid; k < KC; k += 256) {
        float v = 0.99f * ema_cs[k] + 0.01f * (float)counts[k];
        ncs_out[k] = v;
        s += v;
    }
    red[tid] = s;
    __syncthreads();
    for (int m = 128; m > 0; m >>= 1) {
        if (tid < m) red[tid] += red[tid + m];
        __syncthreads();
    }
    if (tid == 0) n_out[0] = red[0];
}

// ---------------- kernel: new_ema_w + new_embedding ----------------
__global__ void k_update(const float* __restrict__ ema_w, const float* __restrict__ dw,
                         const float* __restrict__ ncs, const float* __restrict__ nptr,
                         float* __restrict__ new_ema_w_out, float* __restrict__ new_emb_out) {
    int idx = blockIdx.x * 256 + threadIdx.x;   // 0 .. KC*DIM-1
    float n = nptr[0];
    int k = idx >> 6;
    float nw = 0.99f * ema_w[idx] + 0.01f * dw[idx];
    float cs = (ncs[k] + 1e-5f) / (n + 4096.0f * 1e-5f) * n;
    new_ema_w_out[idx] = nw;
    new_emb_out[idx] = nw / cs;
}

// ---------------- kernel: quantize + straight-through + loss ----------------
__global__ __launch_bounds__(256) void k_quant(
        const float* __restrict__ z, const float* __restrict__ new_emb,
        const int* __restrict__ codes, float* __restrict__ zq_out,
        double* __restrict__ loss_acc) {
    __shared__ double red[256];
    const int nvec = NELEM / 4;
    int t = blockIdx.x * 256 + threadIdx.x;
    int stride = gridDim.x * 256;
    double ls = 0.0;
    for (int v = t; v < nvec; v += stride) {
        int e0 = v * 4;
        int n  = e0 >> 6;
        int d0 = e0 & 63;
        int code = codes[n];
        float4 zq = *(const float4*)&new_emb[(size_t)code * DIM + d0];
        float4 zv = *(const float4*)&z[e0];
        float dx = zq.x - zv.x, dy = zq.y - zv.y, dz = zq.z - zv.z, dw4 = zq.w - zv.w;
        float4 o;
        o.x = zv.x + dx; o.y = zv.y + dy; o.z = zv.z + dz; o.w = zv.w + dw4;
        *(float4*)&zq_out[e0] = o;
        ls += (double)(dx * dx) + (double)(dy * dy) + (double)(dz * dz) + (double)(dw4 * dw4);
    }
    red[threadIdx.x] = ls;
    __syncthreads();
    for (int m = 128; m > 0; m >>= 1) {
        if (threadIdx.x < m) red[threadIdx.x] += red[threadIdx.x + m];
        __syncthreads();
    }
    if (threadIdx.x == 0) atomicAdd(loss_acc, red[0]);
}

__global__ void k_loss(const double* __restrict__ loss_acc, float* __restrict__ out0) {
    out0[0] = (float)(0.25 * (loss_acc[0] / (double)NELEM));
}

// ---------------- launcher ----------------
extern "C" void kernel_launch(void* const* d_in, const int* in_sizes, int n_in,
                              void* d_out, int out_size, void* d_ws, size_t ws_size,
                              hipStream_t stream) {
    const float* z      = (const float*)d_in[0];
    const float* emb    = (const float*)d_in[1];
    const float* ema_cs = (const float*)d_in[2];
    const float* ema_w  = (const float*)d_in[3];
    float* out = (float*)d_out;
    char*  ws  = (char*)d_ws;

    int*    codes_i = (int*)(ws + WS_CODES);
    int*    counts  = (int*)(ws + WS_COUNTS);
    float*  dw      = (float*)(ws + WS_DW);
    float*  e2      = (float*)(ws + WS_E2);
    float*  nptr    = (float*)(ws + WS_N);
    double* lossp   = (double*)(ws + WS_LOSSD);

    // zero the accumulators every call (ws is poisoned, never re-poisoned)
    hipMemsetAsync(counts, 0, sizeof(int) * (size_t)KC, stream);
    hipMemsetAsync(dw, 0, sizeof(float) * (size_t)KC * DIM, stream);
    hipMemsetAsync(lossp, 0, sizeof(double), stream);

    k_e2<<<(KC + 255) / 256, 256, 0, stream>>>(emb, e2);
    k_argmin<<<NROWS / 64, 256, 0, stream>>>(z, emb, e2, codes_i,
                                             out + OUT_CODES, counts, dw);
    k_cluster<<<1, 256, 0, stream>>>(ema_cs, counts, out + OUT_NCS, nptr);
    k_update<<<(KC * DIM) / 256, 256, 0, stream>>>(ema_w, dw, out + OUT_NCS, nptr,
                                                   out + OUT_NEW, out + OUT_EMB);
    k_quant<<<1152, 256, 0, stream>>>(z, out + OUT_EMB, codes_i,
                                      out + OUT_ZQ, lossp);
    k_loss<<<1, 1, 0, stream>>>(lossp, out + OUT_LOSS);
}

// Round 2
// 648.016 us; speedup vs baseline: 1.0492x; 1.0492x over previous
//
#include <hip/hip_runtime.h>

// ---------------- problem constants ----------------
constexpr int KC    = 4096;      // NUM_EMBEDDINGS
constexpr int DIM   = 64;        // EMBEDDING_DIM
constexpr int NROWS = 73728;     // 128*24*1536/64
constexpr int NELEM = 4718592;   // 128*24*1536

typedef _Float16 f16x8 __attribute__((ext_vector_type(8)));
typedef float    f32x4 __attribute__((ext_vector_type(4)));

// ---------------- output layout (floats) ----------------
constexpr size_t OUT_LOSS  = 0;                               // 1
constexpr size_t OUT_ZQ    = 1;                               // NELEM
constexpr size_t OUT_CODES = 1 + (size_t)NELEM;               // NROWS
constexpr size_t OUT_EMB   = OUT_CODES + (size_t)NROWS;       // KC*DIM
constexpr size_t OUT_NCS   = OUT_EMB + (size_t)KC * DIM;      // KC
constexpr size_t OUT_NEW   = OUT_NCS + (size_t)KC;            // KC*DIM

// ---------------- workspace layout (bytes) ----------------
constexpr size_t WS_CODES  = 0;                                        // int[NROWS]
constexpr size_t WS_COUNTS = WS_CODES + sizeof(int) * (size_t)NROWS;   // int[KC]
constexpr size_t WS_DW     = WS_COUNTS + sizeof(int) * (size_t)KC;     // float[KC*DIM]
constexpr size_t WS_E2     = WS_DW + sizeof(float) * (size_t)KC * DIM; // float[KC]
constexpr size_t WS_Z2     = WS_E2 + sizeof(float) * (size_t)KC;       // float[NROWS]
constexpr size_t WS_N      = WS_Z2 + sizeof(float) * (size_t)NROWS;    // float[1]
constexpr size_t WS_LOSSD  = (WS_N + sizeof(float) + 7) & ~(size_t)7;  // double[1]
constexpr size_t WS_EMBSW  = (WS_LOSSD + 8 + 15) & ~(size_t)15;        // 64 tiles * 16384 B

__device__ __forceinline__ void gload_lds16(const void* g, void* l) {
    __builtin_amdgcn_global_load_lds(
        (const __attribute__((address_space(1))) unsigned int*)g,
        (__attribute__((address_space(3))) unsigned int*)l, 16, 0, 0);
}

// ---------------- kernel: per-code squared norms (fp32, matches ref rounding) ----------------
__global__ void k_e2(const float* __restrict__ emb, float* __restrict__ e2) {
    int k = blockIdx.x * blockDim.x + threadIdx.x;
    if (k < KC) {
        const float* e = emb + (size_t)k * DIM;
        float s = 0.f;
        #pragma unroll
        for (int d = 0; d < DIM; ++d) s = fmaf(e[d], e[d], s);
        e2[k] = s;
    }
}

// ---------------- kernel: per-row squared norms ----------------
__global__ void k_z2(const float* __restrict__ z, float* __restrict__ z2) {
    int r = blockIdx.x * 256 + threadIdx.x;
    if (r < NROWS) {
        const float* p = z + (size_t)r * DIM;
        float s = 0.f;
        #pragma unroll
        for (int d = 0; d < DIM; ++d) s = fmaf(p[d], p[d], s);
        z2[r] = s;
    }
}

// ---------------- kernel: pack embedding -> fp16 hi/lo, swizzled for LDS staging ----------------
// tile t (64 codes): bytes [t*16384, +16384). hi region [0,8192): code lc, chunk slot s
// at lc*128 + s*16 holds d-chunk q = s ^ (lc&7) (8 halves). lo region at +8192.
__global__ void k_prep(const float* __restrict__ emb, char* __restrict__ emb_sw) {
    int t = blockIdx.x * 256 + threadIdx.x;   // 0 .. 4096*8-1
    int c = t >> 3, q = t & 7;
    const float* ep = emb + (size_t)c * DIM + q * 8;
    f16x8 hv, lv;
    #pragma unroll
    for (int e = 0; e < 8; ++e) {
        float x = ep[e];
        _Float16 h = (_Float16)x;
        float r = x - (float)h;
        hv[e] = h;
        lv[e] = (_Float16)(r * 2048.0f);   // scale lo by 2^11 -> avoids fp16 denormals
    }
    int tile = c >> 6, lc = c & 63;
    int qs = q ^ (lc & 7);
    char* base = emb_sw + (size_t)tile * 16384 + lc * 128 + qs * 16;
    *(f16x8*)base          = hv;
    *(f16x8*)(base + 8192) = lv;
}

// ---------------- kernel: MFMA distance argmin + EMA scatter ----------------
// 576 blocks x 256 threads (4 waves). Block: 128 rows; wave: 32 rows (2 row-frags).
// Sweep all 4096 codes in 64-code tiles, double-buffered LDS staging of packed emb.
__global__ __launch_bounds__(256) void k_argmin_mfma(
        const float* __restrict__ z, const char* __restrict__ emb_sw,
        const float* __restrict__ e2g, const float* __restrict__ z2g,
        int* __restrict__ codes_i, float* __restrict__ codes_f,
        int* __restrict__ counts, float* __restrict__ dw) {
    __shared__ __align__(16) char lds[49152];   // [0,16K) buf0, [16K,32K) buf1, [32K,48K) e2
    __shared__ int codebuf[128];

    const int tid = threadIdx.x;
    const int l   = tid & 63;
    const int w   = tid >> 6;
    const int lc  = l & 15;      // A-row-in-16 / B-col-in-16 / D-col
    const int lq  = l >> 4;      // k-quarter / D-row-group
    const int blockRow = blockIdx.x * 128;
    const int waveRow  = blockRow + w * 32;

    // ---- stage e2 (16KB) + tile 0 (16KB) ----
    #pragma unroll
    for (int r = 0; r < 4; ++r) {
        gload_lds16((const char*)e2g + r * 4096 + tid * 16, lds + 32768 + r * 4096 + tid * 16);
        gload_lds16(emb_sw + r * 4096 + tid * 16,           lds + r * 4096 + tid * 16);
    }

    // ---- A fragments: z rows -> fp16 hi/lo in registers ----
    f16x8 ah[2][2], al[2][2];
    #pragma unroll
    for (int rt = 0; rt < 2; ++rt)
        #pragma unroll
        for (int h = 0; h < 2; ++h) {
            const float* zp = z + (size_t)(waveRow + rt * 16 + lc) * DIM + h * 32 + lq * 8;
            float4 x0 = *(const float4*)zp;
            float4 x1 = *(const float4*)(zp + 4);
            float xs[8] = {x0.x, x0.y, x0.z, x0.w, x1.x, x1.y, x1.z, x1.w};
            #pragma unroll
            for (int e = 0; e < 8; ++e) {
                _Float16 hh = (_Float16)xs[e];
                float rr = xs[e] - (float)hh;
                ah[rt][h][e] = hh;
                al[rt][h][e] = (_Float16)(rr * 2048.0f);
            }
        }

    // ---- z2 for this lane's output rows (D layout: row = lq*4 + reg + rt*16) ----
    float4 z2a = *(const float4*)&z2g[waveRow + lq * 4];
    float4 z2b = *(const float4*)&z2g[waveRow + 16 + lq * 4];

    float best[2][4];
    int   bestk[2][4];
    #pragma unroll
    for (int rt = 0; rt < 2; ++rt)
        #pragma unroll
        for (int j = 0; j < 4; ++j) { best[rt][j] = INFINITY; bestk[rt][j] = 0; }

    const int rowB = lc * 128;
    const int xm   = lc & 7;
    const int q0   = (lq ^ xm) * 16;        // h=0 chunk (swizzled)
    const int q1   = ((4 + lq) ^ xm) * 16;  // h=1 chunk
    const f32x4 Z4 = {0.f, 0.f, 0.f, 0.f};

    __syncthreads();   // drains vmcnt: tile0 + e2 ready

    #pragma unroll 2
    for (int t = 0; t < 64; ++t) {
        const int cur = (t & 1) * 16384;
        if (t < 63) {   // prefetch next tile into the other buffer
            const char* src = emb_sw + (size_t)(t + 1) * 16384;
            const int nxt = ((t + 1) & 1) * 16384;
            #pragma unroll
            for (int r = 0; r < 4; ++r)
                gload_lds16(src + r * 4096 + tid * 16, lds + nxt + r * 4096 + tid * 16);
        }
        #pragma unroll
        for (int ct = 0; ct < 4; ++ct) {
            const int ob = cur + ct * 2048 + rowB;
            f16x8 bh0 = *(const f16x8*)(lds + ob + q0);
            f16x8 bh1 = *(const f16x8*)(lds + ob + q1);
            f16x8 bl0 = *(const f16x8*)(lds + ob + q0 + 8192);
            f16x8 bl1 = *(const f16x8*)(lds + ob + q1 + 8192);
            float e2c = *(const float*)(lds + 32768 + (t * 64 + ct * 16 + lc) * 4);
            const int kbase = t * 64 + ct * 16 + lc;
            #pragma unroll
            for (int rt = 0; rt < 2; ++rt) {
                f32x4 hh = __builtin_amdgcn_mfma_f32_16x16x32_f16(ah[rt][0], bh0, Z4, 0, 0, 0);
                hh = __builtin_amdgcn_mfma_f32_16x16x32_f16(ah[rt][1], bh1, hh, 0, 0, 0);
                f32x4 cr = __builtin_amdgcn_mfma_f32_16x16x32_f16(ah[rt][0], bl0, Z4, 0, 0, 0);
                cr = __builtin_amdgcn_mfma_f32_16x16x32_f16(ah[rt][1], bl1, cr, 0, 0, 0);
                cr = __builtin_amdgcn_mfma_f32_16x16x32_f16(al[rt][0], bh0, cr, 0, 0, 0);
                cr = __builtin_amdgcn_mfma_f32_16x16x32_f16(al[rt][1], bh1, cr, 0, 0, 0);
                const float4 z2v = rt ? z2b : z2a;
                #pragma unroll
                for (int j = 0; j < 4; ++j) {
                    float g = fmaf(0x1p-11f, cr[j], hh[j]);         // combine split
                    float zz = (j == 0) ? z2v.x : (j == 1) ? z2v.y : (j == 2) ? z2v.z : z2v.w;
                    float s = zz + e2c;                              // fl(z2+e2)
                    float dist = fmaf(-2.0f, g, s);                  // fl(s - 2g)
                    if (dist < best[rt][j]) { best[rt][j] = dist; bestk[rt][j] = kbase; }
                }
            }
        }
        __syncthreads();   // drains vmcnt (next tile staged) + protects buffer reuse
    }

    // ---- butterfly argmin reduce over the 16 lanes of each lq-group ----
    #pragma unroll
    for (int rt = 0; rt < 2; ++rt)
        #pragma unroll
        for (int j = 0; j < 4; ++j) {
            float b = best[rt][j];
            int   k = bestk[rt][j];
            #pragma unroll
            for (int m = 1; m < 16; m <<= 1) {
                float obv = __shfl_xor(b, m, 64);
                int   okv = __shfl_xor(k, m, 64);
                if (obv < b || (obv == b && okv < k)) { b = obv; k = okv; }
            }
            if (lc == 0) codebuf[w * 32 + rt * 16 + lq * 4 + j] = k;
        }

    // ---- scatter: codes, counts, dw (per-wave rows; LDS ops wave-ordered) ----
    const int rl = l >> 1;      // 0..31 local row
    const int dh = l & 1;       // d half
    int code = codebuf[w * 32 + rl];
    size_t rowg = (size_t)waveRow + rl;
    if (dh == 0) {
        codes_i[rowg] = code;
        codes_f[rowg] = (float)code;
        atomicAdd(&counts[code], 1);
    }
    const float* zr = z + rowg * DIM + dh * 32;
    float* dwp = dw + (size_t)code * DIM + dh * 32;
    #pragma unroll
    for (int q = 0; q < 8; ++q) {
        float4 v = *(const float4*)(zr + q * 4);
        atomicAdd(dwp + q * 4 + 0, v.x);
        atomicAdd(dwp + q * 4 + 1, v.y);
        atomicAdd(dwp + q * 4 + 2, v.z);
        atomicAdd(dwp + q * 4 + 3, v.w);
    }
}

// ---------------- kernel: new_cluster_size + n ----------------
__global__ void k_cluster(const float* __restrict__ ema_cs,
                          const int* __restrict__ counts,
                          float* __restrict__ ncs_out, float* __restrict__ n_out) {
    __shared__ float red[256];
    int tid = threadIdx.x;
    float s = 0.f;
    for (int k = tid; k < KC; k += 256) {
        float v = 0.99f * ema_cs[k] + 0.01f * (float)counts[k];
        ncs_out[k] = v;
        s += v;
    }
    red[tid] = s;
    __syncthreads();
    for (int m = 128; m > 0; m >>= 1) {
        if (tid < m) red[tid] += red[tid + m];
        __syncthreads();
    }
    if (tid == 0) n_out[0] = red[0];
}

// ---------------- kernel: new_ema_w + new_embedding ----------------
__global__ void k_update(const float* __restrict__ ema_w, const float* __restrict__ dw,
                         const float* __restrict__ ncs, const float* __restrict__ nptr,
                         float* __restrict__ new_ema_w_out, float* __restrict__ new_emb_out) {
    int idx = blockIdx.x * 256 + threadIdx.x;
    float n = nptr[0];
    int k = idx >> 6;
    float nw = 0.99f * ema_w[idx] + 0.01f * dw[idx];
    float cs = (ncs[k] + 1e-5f) / (n + 4096.0f * 1e-5f) * n;
    new_ema_w_out[idx] = nw;
    new_emb_out[idx] = nw / cs;
}

// ---------------- kernel: quantize + straight-through + loss ----------------
__global__ __launch_bounds__(256) void k_quant(
        const float* __restrict__ z, const float* __restrict__ new_emb,
        const int* __restrict__ codes, float* __restrict__ zq_out,
        double* __restrict__ loss_acc) {
    __shared__ double red[256];
    const int nvec = NELEM / 4;
    int t = blockIdx.x * 256 + threadIdx.x;
    int stride = gridDim.x * 256;
    double ls = 0.0;
    for (int v = t; v < nvec; v += stride) {
        int e0 = v * 4;
        int n  = e0 >> 6;
        int d0 = e0 & 63;
        int code = codes[n];
        float4 zq = *(const float4*)&new_emb[(size_t)code * DIM + d0];
        float4 zv = *(const float4*)&z[e0];
        float dx = zq.x - zv.x, dy = zq.y - zv.y, dz = zq.z - zv.z, dw4 = zq.w - zv.w;
        float4 o;
        o.x = zv.x + dx; o.y = zv.y + dy; o.z = zv.z + dz; o.w = zv.w + dw4;
        *(float4*)&zq_out[e0] = o;
        ls += (double)(dx * dx) + (double)(dy * dy) + (double)(dz * dz) + (double)(dw4 * dw4);
    }
    red[threadIdx.x] = ls;
    __syncthreads();
    for (int m = 128; m > 0; m >>= 1) {
        if (threadIdx.x < m) red[threadIdx.x] += red[threadIdx.x + m];
        __syncthreads();
    }
    if (threadIdx.x == 0) atomicAdd(loss_acc, red[0]);
}

__global__ void k_loss(const double* __restrict__ loss_acc, float* __restrict__ out0) {
    out0[0] = (float)(0.25 * (loss_acc[0] / (double)NELEM));
}

// ---------------- launcher ----------------
extern "C" void kernel_launch(void* const* d_in, const int* in_sizes, int n_in,
                              void* d_out, int out_size, void* d_ws, size_t ws_size,
                              hipStream_t stream) {
    const float* z      = (const float*)d_in[0];
    const float* emb    = (const float*)d_in[1];
    const float* ema_cs = (const float*)d_in[2];
    const float* ema_w  = (const float*)d_in[3];
    float* out = (float*)d_out;
    char*  ws  = (char*)d_ws;

    int*    codes_i = (int*)(ws + WS_CODES);
    int*    counts  = (int*)(ws + WS_COUNTS);
    float*  dw      = (float*)(ws + WS_DW);
    float*  e2      = (float*)(ws + WS_E2);
    float*  z2      = (float*)(ws + WS_Z2);
    float*  nptr    = (float*)(ws + WS_N);
    double* lossp   = (double*)(ws + WS_LOSSD);
    char*   emb_sw  = ws + WS_EMBSW;

    hipMemsetAsync(counts, 0, sizeof(int) * (size_t)KC, stream);
    hipMemsetAsync(dw, 0, sizeof(float) * (size_t)KC * DIM, stream);
    hipMemsetAsync(lossp, 0, sizeof(double), stream);

    k_e2  <<<(KC + 255) / 256, 256, 0, stream>>>(emb, e2);
    k_prep<<<(KC * 8) / 256,   256, 0, stream>>>(emb, emb_sw);
    k_z2  <<<NROWS / 256,      256, 0, stream>>>(z, z2);
    k_argmin_mfma<<<NROWS / 128, 256, 0, stream>>>(z, emb_sw, e2, z2, codes_i,
                                                   out + OUT_CODES, counts, dw);
    k_cluster<<<1, 256, 0, stream>>>(ema_cs, counts, out + OUT_NCS, nptr);
    k_update<<<(KC * DIM) / 256, 256, 0, stream>>>(ema_w, dw, out + OUT_NCS, nptr,
                                                   out + OUT_NEW, out + OUT_EMB);
    k_quant<<<1152, 256, 0, stream>>>(z, out + OUT_EMB, codes_i,
                                      out + OUT_ZQ, lossp);
    k_loss<<<1, 1, 0, stream>>>(lossp, out + OUT_LOSS);
}

// Round 3
// 632.791 us; speedup vs baseline: 1.0745x; 1.0241x over previous
//
#include <hip/hip_runtime.h>

// ---------------- problem constants ----------------
constexpr int KC    = 4096;      // NUM_EMBEDDINGS
constexpr int DIM   = 64;        // EMBEDDING_DIM
constexpr int NROWS = 73728;     // 128*24*1536/64
constexpr int NELEM = 4718592;   // 128*24*1536

typedef _Float16 f16x8 __attribute__((ext_vector_type(8)));
typedef float    f32x4 __attribute__((ext_vector_type(4)));

// ---------------- output layout (floats) ----------------
constexpr size_t OUT_LOSS  = 0;                               // 1
constexpr size_t OUT_ZQ    = 1;                               // NELEM
constexpr size_t OUT_CODES = 1 + (size_t)NELEM;               // NROWS
constexpr size_t OUT_EMB   = OUT_CODES + (size_t)NROWS;       // KC*DIM
constexpr size_t OUT_NCS   = OUT_EMB + (size_t)KC * DIM;      // KC
constexpr size_t OUT_NEW   = OUT_NCS + (size_t)KC;            // KC*DIM

// ---------------- workspace layout (bytes) ----------------
constexpr size_t WS_CODES  = 0;                                        // int[NROWS]
constexpr size_t WS_COUNTS = WS_CODES + sizeof(int) * (size_t)NROWS;   // int[KC]
constexpr size_t WS_DW     = WS_COUNTS + sizeof(int) * (size_t)KC;     // float[KC*DIM]
constexpr size_t WS_E2     = WS_DW + sizeof(float) * (size_t)KC * DIM; // float[KC] (0.5*||e||^2)
constexpr size_t WS_N      = WS_E2 + sizeof(float) * (size_t)KC;       // float[1]
constexpr size_t WS_LOSSD  = (WS_N + sizeof(float) + 7) & ~(size_t)7;  // double[1]
constexpr size_t WS_EMBPK  = (WS_LOSSD + 8 + 15) & ~(size_t)15;        // 1 MB packed emb

// ---------------- kernel: per-code HALF squared norms ----------------
// e2h[k] = 0.5 * sum(e^2). argmin_k (z2 + e2 - 2g) == argmin_k (e2h - g).
__global__ void k_e2(const float* __restrict__ emb, float* __restrict__ e2h) {
    int k = blockIdx.x * blockDim.x + threadIdx.x;
    if (k < KC) {
        const float* e = emb + (size_t)k * DIM;
        float s = 0.f;
        #pragma unroll
        for (int d = 0; d < DIM; ++d) s = fmaf(e[d], e[d], s);
        e2h[k] = 0.5f * s;
    }
}

// ---------------- kernel: pack embedding -> fp16 hi/lo MFMA B-fragments ----------------
// group g (16 codes) at g*4096; frag f (0:hi-h0, 1:hi-h1, 2:lo-h0, 3:lo-h1) at +f*1024;
// lane l at +l*16 holds e[g*16 + (l&15)][h*32 + (l>>4)*8 .. +8].
__global__ void k_prep(const float* __restrict__ emb, char* __restrict__ emb_pk) {
    int t = blockIdx.x * 256 + threadIdx.x;   // 0 .. 32767
    int c = t >> 3, q = t & 7;                // code, d-chunk of 8
    const float* ep = emb + (size_t)c * DIM + q * 8;
    f16x8 hv, lv;
    #pragma unroll
    for (int e = 0; e < 8; ++e) {
        float x = ep[e];
        _Float16 h = (_Float16)x;
        float r = x - (float)h;
        hv[e] = h;
        lv[e] = (_Float16)(r * 2048.0f);   // lo scaled by 2^11 (avoid fp16 denormals)
    }
    int g = c >> 4, lc = c & 15;
    int h = q >> 2, lq = q & 3;
    int lane = lq * 16 + lc;
    char* base = emb_pk + (size_t)g * 4096 + lane * 16;
    *(f16x8*)(base + h * 1024)       = hv;
    *(f16x8*)(base + (2 + h) * 1024) = lv;
}

// ---------------- kernel: MFMA distance argmin + EMA scatter (wave-independent) ----------------
// 576 blocks x 256 threads = 2304 waves; each wave owns 32 rows, sweeps all 4096
// codes in 16-code groups, B-fragments streamed from global (L2-resident 1MB),
// register double-buffered. NO __syncthreads anywhere.
__global__ __launch_bounds__(256) void k_argmin2(
        const float* __restrict__ z, const char* __restrict__ emb_pk,
        const float* __restrict__ e2h,
        int* __restrict__ codes_i, float* __restrict__ codes_f,
        int* __restrict__ counts, float* __restrict__ dw) {
    __shared__ int codebuf[4][32];

    const int tid = threadIdx.x;
    const int l   = tid & 63;
    const int w   = tid >> 6;
    const int lc  = l & 15;
    const int lq  = l >> 4;
    const int waveRow = blockIdx.x * 128 + w * 32;

    // ---- A fragments: 32 z-rows -> fp16 hi/lo in registers ----
    f16x8 ah[2][2], al[2][2];
    #pragma unroll
    for (int rt = 0; rt < 2; ++rt)
        #pragma unroll
        for (int h = 0; h < 2; ++h) {
            const float* zp = z + (size_t)(waveRow + rt * 16 + lc) * DIM + h * 32 + lq * 8;
            float4 x0 = *(const float4*)zp;
            float4 x1 = *(const float4*)(zp + 4);
            float xs[8] = {x0.x, x0.y, x0.z, x0.w, x1.x, x1.y, x1.z, x1.w};
            #pragma unroll
            for (int e = 0; e < 8; ++e) {
                _Float16 hh = (_Float16)xs[e];
                float rr = xs[e] - (float)hh;
                ah[rt][h][e] = hh;
                al[rt][h][e] = (_Float16)(rr * 2048.0f);
            }
        }

    float best[2][4];
    int   bestk[2][4];
    #pragma unroll
    for (int rt = 0; rt < 2; ++rt)
        #pragma unroll
        for (int j = 0; j < 4; ++j) { best[rt][j] = INFINITY; bestk[rt][j] = 0; }

    const f32x4 Z4 = {0.f, 0.f, 0.f, 0.f};
    const char* pk = emb_pk + l * 16;

#define LOADG(EC, B0, B1, B2, B3, G) {                                   \
        const char* p_ = pk + (size_t)(G) * 4096;                        \
        B0 = *(const f16x8*)(p_);                                        \
        B1 = *(const f16x8*)(p_ + 1024);                                 \
        B2 = *(const f16x8*)(p_ + 2048);                                 \
        B3 = *(const f16x8*)(p_ + 3072);                                 \
        EC = e2h[(G) * 16 + lc]; }

#define COMPUTE(B0, B1, B2, B3, EC, G) {                                          \
        _Pragma("unroll")                                                         \
        for (int rt = 0; rt < 2; ++rt) {                                          \
            f32x4 hh = __builtin_amdgcn_mfma_f32_16x16x32_f16(ah[rt][0], B0, Z4, 0, 0, 0); \
            hh = __builtin_amdgcn_mfma_f32_16x16x32_f16(ah[rt][1], B1, hh, 0, 0, 0);       \
            f32x4 cr = __builtin_amdgcn_mfma_f32_16x16x32_f16(ah[rt][0], B2, Z4, 0, 0, 0); \
            cr = __builtin_amdgcn_mfma_f32_16x16x32_f16(ah[rt][1], B3, cr, 0, 0, 0);       \
            cr = __builtin_amdgcn_mfma_f32_16x16x32_f16(al[rt][0], B0, cr, 0, 0, 0);       \
            cr = __builtin_amdgcn_mfma_f32_16x16x32_f16(al[rt][1], B1, cr, 0, 0, 0);       \
            _Pragma("unroll")                                                     \
            for (int j = 0; j < 4; ++j) {                                         \
                float d0 = EC - hh[j];                                            \
                float dist = fmaf(-0x1p-11f, cr[j], d0);                          \
                if (dist < best[rt][j]) { best[rt][j] = dist; bestk[rt][j] = (G) * 16 + lc; } \
            }                                                                     \
        } }

    f16x8 A0, A1, A2, A3, B0, B1, B2, B3;
    float eA, eB;
    LOADG(eA, A0, A1, A2, A3, 0);
    for (int g = 0; g < 256; g += 2) {
        LOADG(eB, B0, B1, B2, B3, g + 1);
        COMPUTE(A0, A1, A2, A3, eA, g);
        if (g + 2 < 256) LOADG(eA, A0, A1, A2, A3, g + 2);
        COMPUTE(B0, B1, B2, B3, eB, g + 1);
    }
#undef LOADG
#undef COMPUTE

    // ---- butterfly argmin reduce over the 16 lanes of each lq-group ----
    #pragma unroll
    for (int rt = 0; rt < 2; ++rt)
        #pragma unroll
        for (int j = 0; j < 4; ++j) {
            float b = best[rt][j];
            int   k = bestk[rt][j];
            #pragma unroll
            for (int m = 1; m < 16; m <<= 1) {
                float obv = __shfl_xor(b, m, 64);
                int   okv = __shfl_xor(k, m, 64);
                if (obv < b || (obv == b && okv < k)) { b = obv; k = okv; }
            }
            if (lc == 0) codebuf[w][rt * 16 + lq * 4 + j] = k;   // D row = lq*4+j
        }

    // ---- scatter: codes, counts, dw (within-wave LDS dep only; no barrier) ----
    const int rl = l >> 1;      // local row 0..31
    const int dh = l & 1;       // dim half
    int code = codebuf[w][rl];
    size_t rowg = (size_t)waveRow + rl;
    if (dh == 0) {
        codes_i[rowg] = code;
        codes_f[rowg] = (float)code;
        atomicAdd(&counts[code], 1);
    }
    const float* zr = z + rowg * DIM + dh * 32;
    float* dwp = dw + (size_t)code * DIM + dh * 32;
    #pragma unroll
    for (int q = 0; q < 8; ++q) {
        float4 v = *(const float4*)(zr + q * 4);
        atomicAdd(dwp + q * 4 + 0, v.x);
        atomicAdd(dwp + q * 4 + 1, v.y);
        atomicAdd(dwp + q * 4 + 2, v.z);
        atomicAdd(dwp + q * 4 + 3, v.w);
    }
}

// ---------------- kernel: new_cluster_size + n ----------------
__global__ void k_cluster(const float* __restrict__ ema_cs,
                          const int* __restrict__ counts,
                          float* __restrict__ ncs_out, float* __restrict__ n_out) {
    __shared__ float red[256];
    int tid = threadIdx.x;
    float s = 0.f;
    for (int k = tid; k < KC; k += 256) {
        float v = 0.99f * ema_cs[k] + 0.01f * (float)counts[k];
        ncs_out[k] = v;
        s += v;
    }
    red[tid] = s;
    __syncthreads();
    for (int m = 128; m > 0; m >>= 1) {
        if (tid < m) red[tid] += red[tid + m];
        __syncthreads();
    }
    if (tid == 0) n_out[0] = red[0];
}

// ---------------- kernel: new_ema_w + new_embedding ----------------
__global__ void k_update(const float* __restrict__ ema_w, const float* __restrict__ dw,
                         const float* __restrict__ ncs, const float* __restrict__ nptr,
                         float* __restrict__ new_ema_w_out, float* __restrict__ new_emb_out) {
    int idx = blockIdx.x * 256 + threadIdx.x;
    float n = nptr[0];
    int k = idx >> 6;
    float nw = 0.99f * ema_w[idx] + 0.01f * dw[idx];
    float cs = (ncs[k] + 1e-5f) / (n + 4096.0f * 1e-5f) * n;
    new_ema_w_out[idx] = nw;
    new_emb_out[idx] = nw / cs;
}

// ---------------- kernel: quantize + straight-through + loss ----------------
__global__ __launch_bounds__(256) void k_quant(
        const float* __restrict__ z, const float* __restrict__ new_emb,
        const int* __restrict__ codes, float* __restrict__ zq_out,
        double* __restrict__ loss_acc) {
    __shared__ double red[256];
    const int nvec = NELEM / 4;
    int t = blockIdx.x * 256 + threadIdx.x;
    int stride = gridDim.x * 256;
    double ls = 0.0;
    for (int v = t; v < nvec; v += stride) {
        int e0 = v * 4;
        int n  = e0 >> 6;
        int d0 = e0 & 63;
        int code = codes[n];
        float4 zq = *(const float4*)&new_emb[(size_t)code * DIM + d0];
        float4 zv = *(const float4*)&z[e0];
        float dx = zq.x - zv.x, dy = zq.y - zv.y, dz = zq.z - zv.z, dw4 = zq.w - zv.w;
        float4 o;
        o.x = zv.x + dx; o.y = zv.y + dy; o.z = zv.z + dz; o.w = zv.w + dw4;
        *(float4*)&zq_out[e0] = o;
        ls += (double)(dx * dx) + (double)(dy * dy) + (double)(dz * dz) + (double)(dw4 * dw4);
    }
    red[threadIdx.x] = ls;
    __syncthreads();
    for (int m = 128; m > 0; m >>= 1) {
        if (threadIdx.x < m) red[threadIdx.x] += red[threadIdx.x + m];
        __syncthreads();
    }
    if (threadIdx.x == 0) atomicAdd(loss_acc, red[0]);
}

__global__ void k_loss(const double* __restrict__ loss_acc, float* __restrict__ out0) {
    out0[0] = (float)(0.25 * (loss_acc[0] / (double)NELEM));
}

// ---------------- launcher ----------------
extern "C" void kernel_launch(void* const* d_in, const int* in_sizes, int n_in,
                              void* d_out, int out_size, void* d_ws, size_t ws_size,
                              hipStream_t stream) {
    const float* z      = (const float*)d_in[0];
    const float* emb    = (const float*)d_in[1];
    const float* ema_cs = (const float*)d_in[2];
    const float* ema_w  = (const float*)d_in[3];
    float* out = (float*)d_out;
    char*  ws  = (char*)d_ws;

    int*    codes_i = (int*)(ws + WS_CODES);
    int*    counts  = (int*)(ws + WS_COUNTS);
    float*  dw      = (float*)(ws + WS_DW);
    float*  e2h     = (float*)(ws + WS_E2);
    float*  nptr    = (float*)(ws + WS_N);
    double* lossp   = (double*)(ws + WS_LOSSD);
    char*   emb_pk  = ws + WS_EMBPK;

    hipMemsetAsync(counts, 0, sizeof(int) * (size_t)KC, stream);
    hipMemsetAsync(dw, 0, sizeof(float) * (size_t)KC * DIM, stream);
    hipMemsetAsync(lossp, 0, sizeof(double), stream);

    k_e2  <<<(KC + 255) / 256, 256, 0, stream>>>(emb, e2h);
    k_prep<<<(KC * 8) / 256,   256, 0, stream>>>(emb, emb_pk);
    k_argmin2<<<NROWS / 128, 256, 0, stream>>>(z, emb_pk, e2h, codes_i,
                                               out + OUT_CODES, counts, dw);
    k_cluster<<<1, 256, 0, stream>>>(ema_cs, counts, out + OUT_NCS, nptr);
    k_update<<<(KC * DIM) / 256, 256, 0, stream>>>(ema_w, dw, out + OUT_NCS, nptr,
                                                   out + OUT_NEW, out + OUT_EMB);
    k_quant<<<1152, 256, 0, stream>>>(z, out + OUT_EMB, codes_i,
                                      out + OUT_ZQ, lossp);
    k_loss<<<1, 1, 0, stream>>>(lossp, out + OUT_LOSS);
}

// Round 4
// 227.514 us; speedup vs baseline: 2.9885x; 2.7813x over previous
//
#include <hip/hip_runtime.h>

// ---------------- problem constants ----------------
constexpr int KC    = 4096;      // NUM_EMBEDDINGS
constexpr int DIM   = 64;        // EMBEDDING_DIM
constexpr int NROWS = 73728;     // 128*24*1536/64
constexpr int NELEM = 4718592;   // 128*24*1536

typedef _Float16 f16x8 __attribute__((ext_vector_type(8)));
typedef float    f32x4 __attribute__((ext_vector_type(4)));

// ---------------- output layout (floats) ----------------
constexpr size_t OUT_LOSS  = 0;                               // 1
constexpr size_t OUT_ZQ    = 1;                               // NELEM
constexpr size_t OUT_CODES = 1 + (size_t)NELEM;               // NROWS
constexpr size_t OUT_EMB   = OUT_CODES + (size_t)NROWS;       // KC*DIM
constexpr size_t OUT_NCS   = OUT_EMB + (size_t)KC * DIM;      // KC
constexpr size_t OUT_NEW   = OUT_NCS + (size_t)KC;            // KC*DIM

// ---------------- workspace layout (bytes) ----------------
constexpr size_t alignup(size_t x, size_t a) { return (x + a - 1) & ~(a - 1); }
constexpr size_t WS_CODES  = 0;                                            // int[NROWS]
constexpr size_t WS_COUNTS = WS_CODES + sizeof(int) * (size_t)NROWS;       // int[KC]
constexpr size_t WS_OFFS   = WS_COUNTS + sizeof(int) * (size_t)KC;         // int[KC+1]
constexpr size_t WS_CURSOR = alignup(WS_OFFS + sizeof(int) * (KC + 1), 16);// int[KC]
constexpr size_t WS_SORTED = WS_CURSOR + sizeof(int) * (size_t)KC;         // int[NROWS]
constexpr size_t WS_DW     = alignup(WS_SORTED + sizeof(int) * (size_t)NROWS, 16); // float[KC*DIM]
constexpr size_t WS_E2     = WS_DW + sizeof(float) * (size_t)KC * DIM;     // float[KC]
constexpr size_t WS_N      = WS_E2 + sizeof(float) * (size_t)KC;           // float[1]
constexpr size_t WS_LOSSD  = alignup(WS_N + sizeof(float), 8);             // double[1]
constexpr size_t WS_EMBPK  = alignup(WS_LOSSD + 8, 16);                    // 1 MB packed emb

// ---------------- kernel: per-code HALF squared norms ----------------
// e2h[k] = 0.5*sum(e^2). argmin_k(z2 + e2 - 2g) == argmin_k(e2h - g).
__global__ void k_e2(const float* __restrict__ emb, float* __restrict__ e2h) {
    int k = blockIdx.x * blockDim.x + threadIdx.x;
    if (k < KC) {
        const float* e = emb + (size_t)k * DIM;
        float s = 0.f;
        #pragma unroll
        for (int d = 0; d < DIM; ++d) s = fmaf(e[d], e[d], s);
        e2h[k] = 0.5f * s;
    }
}

// ---------------- kernel: pack embedding -> fp16 hi/lo MFMA B-fragments ----------------
// group g (16 codes) at g*4096; frag f (0:hi-h0, 1:hi-h1, 2:lo-h0, 3:lo-h1) at +f*1024;
// lane l at +l*16 holds e[g*16 + (l&15)][h*32 + (l>>4)*8 .. +8].
__global__ void k_prep(const float* __restrict__ emb, char* __restrict__ emb_pk) {
    int t = blockIdx.x * 256 + threadIdx.x;   // 0 .. 32767
    int c = t >> 3, q = t & 7;                // code, d-chunk of 8
    const float* ep = emb + (size_t)c * DIM + q * 8;
    f16x8 hv, lv;
    #pragma unroll
    for (int e = 0; e < 8; ++e) {
        float x = ep[e];
        _Float16 h = (_Float16)x;
        float r = x - (float)h;
        hv[e] = h;
        lv[e] = (_Float16)(r * 2048.0f);   // lo scaled by 2^11 (avoid fp16 denormals)
    }
    int g = c >> 4, lc = c & 15;
    int h = q >> 2, lq = q & 3;
    int lane = lq * 16 + lc;
    char* base = emb_pk + (size_t)g * 4096 + lane * 16;
    *(f16x8*)(base + h * 1024)       = hv;
    *(f16x8*)(base + (2 + h) * 1024) = lv;
}

// ---------------- kernel: MFMA distance argmin (codes only, no fp32 scatter) ----------------
// 2304 blocks x 128 threads (2 waves). Block owns 32 rows; wave w sweeps codes
// [w*2048, (w+1)*2048) in 16-code groups streamed from L2, triple-buffered.
__global__ __launch_bounds__(128) void k_argmin3(
        const float* __restrict__ z, const char* __restrict__ emb_pk,
        const float* __restrict__ e2h,
        int* __restrict__ codes_i, float* __restrict__ codes_f,
        int* __restrict__ counts) {
    __shared__ float bd[2][32];
    __shared__ int   bk[2][32];

    const int tid = threadIdx.x;
    const int l   = tid & 63;
    const int w   = tid >> 6;
    const int lc  = l & 15;
    const int lq  = l >> 4;
    const int waveRow = blockIdx.x * 32;
    const int gBase   = w * 128;

    // ---- A fragments: 32 z-rows -> fp16 hi/lo in registers ----
    f16x8 ah[2][2], al[2][2];
    #pragma unroll
    for (int rt = 0; rt < 2; ++rt)
        #pragma unroll
        for (int h = 0; h < 2; ++h) {
            const float* zp = z + (size_t)(waveRow + rt * 16 + lc) * DIM + h * 32 + lq * 8;
            float4 x0 = *(const float4*)zp;
            float4 x1 = *(const float4*)(zp + 4);
            float xs[8] = {x0.x, x0.y, x0.z, x0.w, x1.x, x1.y, x1.z, x1.w};
            #pragma unroll
            for (int e = 0; e < 8; ++e) {
                _Float16 hh = (_Float16)xs[e];
                float rr = xs[e] - (float)hh;
                ah[rt][h][e] = hh;
                al[rt][h][e] = (_Float16)(rr * 2048.0f);
            }
        }

    float best[2][4];
    int   bestk[2][4];
    #pragma unroll
    for (int rt = 0; rt < 2; ++rt)
        #pragma unroll
        for (int j = 0; j < 4; ++j) { best[rt][j] = INFINITY; bestk[rt][j] = 0; }

    const f32x4 Z4 = {0.f, 0.f, 0.f, 0.f};
    const char* pk = emb_pk + l * 16;

#define LOADG(EC, B0, B1, B2, B3, G) {                                   \
        const char* p_ = pk + (size_t)(G) * 4096;                        \
        B0 = *(const f16x8*)(p_);                                        \
        B1 = *(const f16x8*)(p_ + 1024);                                 \
        B2 = *(const f16x8*)(p_ + 2048);                                 \
        B3 = *(const f16x8*)(p_ + 3072);                                 \
        EC = e2h[(G) * 16 + lc]; }

#define COMPUTE(B0, B1, B2, B3, EC, G) {                                          \
        _Pragma("unroll")                                                         \
        for (int rt = 0; rt < 2; ++rt) {                                          \
            f32x4 hh = __builtin_amdgcn_mfma_f32_16x16x32_f16(ah[rt][0], B0, Z4, 0, 0, 0); \
            hh = __builtin_amdgcn_mfma_f32_16x16x32_f16(ah[rt][1], B1, hh, 0, 0, 0);       \
            f32x4 cr = __builtin_amdgcn_mfma_f32_16x16x32_f16(ah[rt][0], B2, Z4, 0, 0, 0); \
            cr = __builtin_amdgcn_mfma_f32_16x16x32_f16(ah[rt][1], B3, cr, 0, 0, 0);       \
            cr = __builtin_amdgcn_mfma_f32_16x16x32_f16(al[rt][0], B0, cr, 0, 0, 0);       \
            cr = __builtin_amdgcn_mfma_f32_16x16x32_f16(al[rt][1], B1, cr, 0, 0, 0);       \
            _Pragma("unroll")                                                     \
            for (int j = 0; j < 4; ++j) {                                         \
                float d0 = EC - hh[j];                                            \
                float dist = fmaf(-0x1p-11f, cr[j], d0);                          \
                if (dist < best[rt][j]) { best[rt][j] = dist; bestk[rt][j] = (G) * 16 + lc; } \
            }                                                                     \
        } }

    {
        f16x8 A0, A1, A2, A3, B0, B1, B2, B3, C0, C1, C2, C3;
        float eA, eB, eC;
        LOADG(eA, A0, A1, A2, A3, gBase + 0);
        LOADG(eB, B0, B1, B2, B3, gBase + 1);
        int g = 0;
        for (; g + 4 < 128; g += 3) {
            LOADG(eC, C0, C1, C2, C3, gBase + g + 2);
            COMPUTE(A0, A1, A2, A3, eA, gBase + g);
            LOADG(eA, A0, A1, A2, A3, gBase + g + 3);
            COMPUTE(B0, B1, B2, B3, eB, gBase + g + 1);
            LOADG(eB, B0, B1, B2, B3, gBase + g + 4);
            COMPUTE(C0, C1, C2, C3, eC, gBase + g + 2);
        }
        // g == 123 exit: A holds 126, B holds 127
        COMPUTE(A0, A1, A2, A3, eA, gBase + 126);
        COMPUTE(B0, B1, B2, B3, eB, gBase + 127);
    }
#undef LOADG
#undef COMPUTE

    // ---- butterfly argmin reduce over the 16 lanes of each lq-group ----
    #pragma unroll
    for (int rt = 0; rt < 2; ++rt)
        #pragma unroll
        for (int j = 0; j < 4; ++j) {
            float b = best[rt][j];
            int   k = bestk[rt][j];
            #pragma unroll
            for (int m = 1; m < 16; m <<= 1) {
                float obv = __shfl_xor(b, m, 64);
                int   okv = __shfl_xor(k, m, 64);
                if (obv < b || (obv == b && okv < k)) { b = obv; k = okv; }
            }
            if (lc == 0) {                       // D row = rt*16 + lq*4 + j
                bd[w][rt * 16 + lq * 4 + j] = b;
                bk[w][rt * 16 + lq * 4 + j] = k;
            }
        }
    __syncthreads();

    // ---- combine the two waves' halves; emit codes + int counts ----
    if (tid < 32) {
        float d0 = bd[0][tid], d1 = bd[1][tid];
        int   k0 = bk[0][tid], k1 = bk[1][tid];
        int code = (d1 < d0) ? k1 : k0;   // tie -> k0 (always lower index)
        size_t rowg = (size_t)waveRow + tid;
        codes_i[rowg] = code;
        codes_f[rowg] = (float)code;
        atomicAdd(&counts[code], 1);
    }
}

// ---------------- kernel: exclusive prefix sum of counts -> offsets, cursor ----------------
__global__ void k_scan(const int* __restrict__ counts,
                       int* __restrict__ offsets, int* __restrict__ cursor) {
    __shared__ int part[256];
    int tid = threadIdx.x;
    int base = tid * 16;
    int loc[16];
    int s = 0;
    #pragma unroll
    for (int j = 0; j < 16; ++j) { loc[j] = s; s += counts[base + j]; }
    part[tid] = s;
    __syncthreads();
    for (int off = 1; off < 256; off <<= 1) {
        int v = (tid >= off) ? part[tid - off] : 0;
        __syncthreads();
        part[tid] += v;
        __syncthreads();
    }
    int excl = part[tid] - s;
    #pragma unroll
    for (int j = 0; j < 16; ++j) {
        int o = excl + loc[j];
        offsets[base + j] = o;
        cursor[base + j]  = o;
    }
    if (tid == 255) offsets[KC] = excl + s;
}

// ---------------- kernel: scatter row indices into code-sorted order ----------------
__global__ void k_scatteridx(const int* __restrict__ codes_i,
                             int* __restrict__ cursor, int* __restrict__ sorted_rows) {
    int r = blockIdx.x * 256 + threadIdx.x;
    if (r < NROWS) {
        int c = codes_i[r];
        int p = atomicAdd(&cursor[c], 1);
        sorted_rows[p] = r;
    }
}

// ---------------- kernel: segmented sum -> dw (one block per code, coalesced) ----------------
__global__ __launch_bounds__(64) void k_dwsum(
        const float* __restrict__ z, const int* __restrict__ offsets,
        const int* __restrict__ sorted_rows, float* __restrict__ dw) {
    int k = blockIdx.x, tid = threadIdx.x;
    int beg = offsets[k], end = offsets[k + 1];
    float a0 = 0.f, a1 = 0.f, a2 = 0.f, a3 = 0.f;
    int i = beg;
    for (; i + 3 < end; i += 4) {
        int r0 = sorted_rows[i], r1 = sorted_rows[i + 1];
        int r2 = sorted_rows[i + 2], r3 = sorted_rows[i + 3];
        a0 += z[(size_t)r0 * DIM + tid];
        a1 += z[(size_t)r1 * DIM + tid];
        a2 += z[(size_t)r2 * DIM + tid];
        a3 += z[(size_t)r3 * DIM + tid];
    }
    for (; i < end; ++i) a0 += z[(size_t)sorted_rows[i] * DIM + tid];
    dw[(size_t)k * DIM + tid] = (a0 + a1) + (a2 + a3);
}

// ---------------- kernel: new_cluster_size + n ----------------
__global__ void k_cluster(const float* __restrict__ ema_cs,
                          const int* __restrict__ counts,
                          float* __restrict__ ncs_out, float* __restrict__ n_out) {
    __shared__ float red[256];
    int tid = threadIdx.x;
    float s = 0.f;
    for (int k = tid; k < KC; k += 256) {
        float v = 0.99f * ema_cs[k] + 0.01f * (float)counts[k];
        ncs_out[k] = v;
        s += v;
    }
    red[tid] = s;
    __syncthreads();
    for (int m = 128; m > 0; m >>= 1) {
        if (tid < m) red[tid] += red[tid + m];
        __syncthreads();
    }
    if (tid == 0) n_out[0] = red[0];
}

// ---------------- kernel: new_ema_w + new_embedding ----------------
__global__ void k_update(const float* __restrict__ ema_w, const float* __restrict__ dw,
                         const float* __restrict__ ncs, const float* __restrict__ nptr,
                         float* __restrict__ new_ema_w_out, float* __restrict__ new_emb_out) {
    int idx = blockIdx.x * 256 + threadIdx.x;
    float n = nptr[0];
    int k = idx >> 6;
    float nw = 0.99f * ema_w[idx] + 0.01f * dw[idx];
    float cs = (ncs[k] + 1e-5f) / (n + 4096.0f * 1e-5f) * n;
    new_ema_w_out[idx] = nw;
    new_emb_out[idx] = nw / cs;
}

// ---------------- kernel: quantize + straight-through + loss ----------------
__global__ __launch_bounds__(256) void k_quant(
        const float* __restrict__ z, const float* __restrict__ new_emb,
        const int* __restrict__ codes, float* __restrict__ zq_out,
        double* __restrict__ loss_acc) {
    __shared__ double red[256];
    const int nvec = NELEM / 4;
    int t = blockIdx.x * 256 + threadIdx.x;
    int stride = gridDim.x * 256;
    double ls = 0.0;
    for (int v = t; v < nvec; v += stride) {
        int e0 = v * 4;
        int n  = e0 >> 6;
        int d0 = e0 & 63;
        int code = codes[n];
        float4 zq = *(const float4*)&new_emb[(size_t)code * DIM + d0];
        float4 zv = *(const float4*)&z[e0];
        float dx = zq.x - zv.x, dy = zq.y - zv.y, dz = zq.z - zv.z, dw4 = zq.w - zv.w;
        float4 o;
        o.x = zv.x + dx; o.y = zv.y + dy; o.z = zv.z + dz; o.w = zv.w + dw4;
        *(float4*)&zq_out[e0] = o;
        ls += (double)(dx * dx) + (double)(dy * dy) + (double)(dz * dz) + (double)(dw4 * dw4);
    }
    red[threadIdx.x] = ls;
    __syncthreads();
    for (int m = 128; m > 0; m >>= 1) {
        if (threadIdx.x < m) red[threadIdx.x] += red[threadIdx.x + m];
        __syncthreads();
    }
    if (threadIdx.x == 0) atomicAdd(loss_acc, red[0]);
}

__global__ void k_loss(const double* __restrict__ loss_acc, float* __restrict__ out0) {
    out0[0] = (float)(0.25 * (loss_acc[0] / (double)NELEM));
}

// ---------------- launcher ----------------
extern "C" void kernel_launch(void* const* d_in, const int* in_sizes, int n_in,
                              void* d_out, int out_size, void* d_ws, size_t ws_size,
                              hipStream_t stream) {
    const float* z      = (const float*)d_in[0];
    const float* emb    = (const float*)d_in[1];
    const float* ema_cs = (const float*)d_in[2];
    const float* ema_w  = (const float*)d_in[3];
    float* out = (float*)d_out;
    char*  ws  = (char*)d_ws;

    int*    codes_i = (int*)(ws + WS_CODES);
    int*    counts  = (int*)(ws + WS_COUNTS);
    int*    offsets = (int*)(ws + WS_OFFS);
    int*    cursor  = (int*)(ws + WS_CURSOR);
    int*    sorted  = (int*)(ws + WS_SORTED);
    float*  dw      = (float*)(ws + WS_DW);
    float*  e2h     = (float*)(ws + WS_E2);
    float*  nptr    = (float*)(ws + WS_N);
    double* lossp   = (double*)(ws + WS_LOSSD);
    char*   emb_pk  = ws + WS_EMBPK;

    hipMemsetAsync(counts, 0, sizeof(int) * (size_t)KC, stream);
    hipMemsetAsync(lossp, 0, sizeof(double), stream);

    k_e2  <<<(KC + 255) / 256, 256, 0, stream>>>(emb, e2h);
    k_prep<<<(KC * 8) / 256,   256, 0, stream>>>(emb, emb_pk);
    k_argmin3<<<NROWS / 32, 128, 0, stream>>>(z, emb_pk, e2h, codes_i,
                                              out + OUT_CODES, counts);
    k_scan<<<1, 256, 0, stream>>>(counts, offsets, cursor);
    k_scatteridx<<<(NROWS + 255) / 256, 256, 0, stream>>>(codes_i, cursor, sorted);
    k_dwsum<<<KC, 64, 0, stream>>>(z, offsets, sorted, dw);
    k_cluster<<<1, 256, 0, stream>>>(ema_cs, counts, out + OUT_NCS, nptr);
    k_update<<<(KC * DIM) / 256, 256, 0, stream>>>(ema_w, dw, out + OUT_NCS, nptr,
                                                   out + OUT_NEW, out + OUT_EMB);
    k_quant<<<1152, 256, 0, stream>>>(z, out + OUT_EMB, codes_i,
                                      out + OUT_ZQ, lossp);
    k_loss<<<1, 1, 0, stream>>>(lossp, out + OUT_LOSS);
}

// Round 5
// 220.132 us; speedup vs baseline: 3.0887x; 1.0335x over previous
//
#include <hip/hip_runtime.h>

// ---------------- problem constants ----------------
constexpr int KC    = 4096;      // NUM_EMBEDDINGS
constexpr int DIM   = 64;        // EMBEDDING_DIM
constexpr int NROWS = 73728;     // 128*24*1536/64
constexpr int NELEM = 4718592;   // 128*24*1536

typedef _Float16 f16x8 __attribute__((ext_vector_type(8)));
typedef float    f32x4 __attribute__((ext_vector_type(4)));

// ---------------- output layout (floats) ----------------
constexpr size_t OUT_LOSS  = 0;                               // 1
constexpr size_t OUT_ZQ    = 1;                               // NELEM
constexpr size_t OUT_CODES = 1 + (size_t)NELEM;               // NROWS
constexpr size_t OUT_EMB   = OUT_CODES + (size_t)NROWS;       // KC*DIM
constexpr size_t OUT_NCS   = OUT_EMB + (size_t)KC * DIM;      // KC
constexpr size_t OUT_NEW   = OUT_NCS + (size_t)KC;            // KC*DIM

// ---------------- workspace layout (bytes) ----------------
constexpr size_t alignup(size_t x, size_t a) { return (x + a - 1) & ~(a - 1); }
constexpr size_t WS_CODES  = 0;                                            // int[NROWS]
constexpr size_t WS_COUNTS = WS_CODES + sizeof(int) * (size_t)NROWS;       // int[KC]
constexpr size_t WS_OFFS   = WS_COUNTS + sizeof(int) * (size_t)KC;         // int[KC+1]
constexpr size_t WS_CURSOR = alignup(WS_OFFS + sizeof(int) * (KC + 1), 16);// int[KC]
constexpr size_t WS_SORTED = WS_CURSOR + sizeof(int) * (size_t)KC;         // int[NROWS]
constexpr size_t WS_DW     = alignup(WS_SORTED + sizeof(int) * (size_t)NROWS, 16); // float[KC*DIM]
constexpr size_t WS_E2     = WS_DW + sizeof(float) * (size_t)KC * DIM;     // float[KC]
constexpr size_t WS_N      = WS_E2 + sizeof(float) * (size_t)KC;           // float[1]
constexpr size_t WS_LOSSD  = alignup(WS_N + sizeof(float), 8);             // double[1]
constexpr size_t WS_EMBPK  = alignup(WS_LOSSD + 8, 16);                    // 1 MB packed emb

// ---------------- kernel: pack emb -> fp16 hi/lo B-frags + e2h + zero counts ----------
// group g (16 codes) at g*4096; frag f (0:hi-h0, 1:hi-h1, 2:lo-h0, 3:lo-h1) at +f*1024;
// lane l at +l*16 holds e[g*16 + (l&15)][h*32 + (l>>4)*8 .. +8].
// Also: e2h[k] = 0.5*sum(e[k]^2)  (argmin_k(z2+e2-2g) == argmin_k(e2h-g)),
// and zeroes counts (128 blocks x 32 ints).
__global__ void k_prep(const float* __restrict__ emb, char* __restrict__ emb_pk,
                       float* __restrict__ e2h, int* __restrict__ counts) {
    if (threadIdx.x < 32) counts[blockIdx.x * 32 + threadIdx.x] = 0;
    int t = blockIdx.x * 256 + threadIdx.x;   // 0 .. 32767
    int c = t >> 3, q = t & 7;                // code, d-chunk of 8
    const float* ep = emb + (size_t)c * DIM + q * 8;
    f16x8 hv, lv;
    float s = 0.f;
    #pragma unroll
    for (int e = 0; e < 8; ++e) {
        float x = ep[e];
        _Float16 h = (_Float16)x;
        float r = x - (float)h;
        hv[e] = h;
        lv[e] = (_Float16)(r * 2048.0f);   // lo scaled by 2^11 (avoid fp16 denormals)
        s = fmaf(x, x, s);
    }
    // 8-lane tree sum (lanes t, same code, consecutive)
    s += __shfl_xor(s, 1, 64);
    s += __shfl_xor(s, 2, 64);
    s += __shfl_xor(s, 4, 64);
    if (q == 0) e2h[c] = 0.5f * s;
    int g = c >> 4, lc = c & 15;
    int h = q >> 2, lq = q & 3;
    int lane = lq * 16 + lc;
    char* base = emb_pk + (size_t)g * 4096 + lane * 16;
    *(f16x8*)(base + h * 1024)       = hv;
    *(f16x8*)(base + (2 + h) * 1024) = lv;
}

// ---------------- kernel: MFMA distance argmin (L1-shared code stream) ----------------
// 576 blocks x 256 threads (4 waves). Each wave owns 32 rows and sweeps ALL 4096
// codes; the 4 waves stream the SAME groups in loose lockstep -> L1 serves 3/4 of
// the B traffic. Triple-buffered register pipeline, no __syncthreads.
// A-fragments hold NEGATED z (hi/lo), so MFMA with C-init=e2c gives dist directly.
__global__ __launch_bounds__(256) void k_argmin4(
        const float* __restrict__ z, const char* __restrict__ emb_pk,
        const float* __restrict__ e2h,
        int* __restrict__ codes_i, float* __restrict__ codes_f,
        int* __restrict__ counts) {
    __shared__ int codebuf[4][32];

    const int tid = threadIdx.x;
    const int l   = tid & 63;
    const int w   = tid >> 6;
    const int lc  = l & 15;
    const int lq  = l >> 4;
    const int waveRow = blockIdx.x * 128 + w * 32;

    // ---- A fragments: 32 z-rows -> NEGATED fp16 hi/lo in registers ----
    f16x8 ah[2][2], al[2][2];
    #pragma unroll
    for (int rt = 0; rt < 2; ++rt)
        #pragma unroll
        for (int h = 0; h < 2; ++h) {
            const float* zp = z + (size_t)(waveRow + rt * 16 + lc) * DIM + h * 32 + lq * 8;
            float4 x0 = *(const float4*)zp;
            float4 x1 = *(const float4*)(zp + 4);
            float xs[8] = {x0.x, x0.y, x0.z, x0.w, x1.x, x1.y, x1.z, x1.w};
            #pragma unroll
            for (int e = 0; e < 8; ++e) {
                _Float16 hh = (_Float16)xs[e];
                float rr = xs[e] - (float)hh;
                ah[rt][h][e] = -hh;
                al[rt][h][e] = -(_Float16)(rr * 2048.0f);
            }
        }

    float best[2][4];
    int   bestk[2][4];
    #pragma unroll
    for (int rt = 0; rt < 2; ++rt)
        #pragma unroll
        for (int j = 0; j < 4; ++j) { best[rt][j] = INFINITY; bestk[rt][j] = 0; }

    const f32x4 Z4 = {0.f, 0.f, 0.f, 0.f};
    const char* pk = emb_pk + l * 16;

#define LOADG(EC, B0, B1, B2, B3, G) {                                   \
        const char* p_ = pk + (size_t)(G) * 4096;                        \
        B0 = *(const f16x8*)(p_);                                        \
        B1 = *(const f16x8*)(p_ + 1024);                                 \
        B2 = *(const f16x8*)(p_ + 2048);                                 \
        B3 = *(const f16x8*)(p_ + 3072);                                 \
        EC = e2h[(G) * 16 + lc]; }

    // hh = e2c - z_hi.e_hi ; cr = -2048*(z_hi.e_lo + z_lo.e_hi); dist = hh + 2^-11*cr
#define COMPUTE(B0, B1, B2, B3, EC, G) {                                          \
        f32x4 Ce; Ce[0] = EC; Ce[1] = EC; Ce[2] = EC; Ce[3] = EC;                 \
        _Pragma("unroll")                                                         \
        for (int rt = 0; rt < 2; ++rt) {                                          \
            f32x4 hh = __builtin_amdgcn_mfma_f32_16x16x32_f16(ah[rt][0], B0, Ce, 0, 0, 0); \
            hh = __builtin_amdgcn_mfma_f32_16x16x32_f16(ah[rt][1], B1, hh, 0, 0, 0);       \
            f32x4 cr = __builtin_amdgcn_mfma_f32_16x16x32_f16(ah[rt][0], B2, Z4, 0, 0, 0); \
            cr = __builtin_amdgcn_mfma_f32_16x16x32_f16(ah[rt][1], B3, cr, 0, 0, 0);       \
            cr = __builtin_amdgcn_mfma_f32_16x16x32_f16(al[rt][0], B0, cr, 0, 0, 0);       \
            cr = __builtin_amdgcn_mfma_f32_16x16x32_f16(al[rt][1], B1, cr, 0, 0, 0);       \
            _Pragma("unroll")                                                     \
            for (int j = 0; j < 4; ++j) {                                         \
                float dist = fmaf(0x1p-11f, cr[j], hh[j]);                        \
                if (dist < best[rt][j]) { best[rt][j] = dist; bestk[rt][j] = (G) * 16 + lc; } \
            }                                                                     \
        } }

    {
        f16x8 A0, A1, A2, A3, B0, B1, B2, B3, C0, C1, C2, C3;
        float eA, eB, eC;
        LOADG(eA, A0, A1, A2, A3, 0);
        LOADG(eB, B0, B1, B2, B3, 1);
        int g = 0;
        for (; g + 4 < 256; g += 3) {
            LOADG(eC, C0, C1, C2, C3, g + 2);
            COMPUTE(A0, A1, A2, A3, eA, g);
            LOADG(eA, A0, A1, A2, A3, g + 3);
            COMPUTE(B0, B1, B2, B3, eB, g + 1);
            LOADG(eB, B0, B1, B2, B3, g + 4);
            COMPUTE(C0, C1, C2, C3, eC, g + 2);
        }
        // exit with g == 252: A holds 252, B holds 253
        LOADG(eC, C0, C1, C2, C3, 254);
        COMPUTE(A0, A1, A2, A3, eA, 252);
        LOADG(eA, A0, A1, A2, A3, 255);
        COMPUTE(B0, B1, B2, B3, eB, 253);
        COMPUTE(C0, C1, C2, C3, eC, 254);
        COMPUTE(A0, A1, A2, A3, eA, 255);
    }
#undef LOADG
#undef COMPUTE

    // ---- butterfly argmin reduce over the 16 lanes of each lq-group ----
    #pragma unroll
    for (int rt = 0; rt < 2; ++rt)
        #pragma unroll
        for (int j = 0; j < 4; ++j) {
            float b = best[rt][j];
            int   k = bestk[rt][j];
            #pragma unroll
            for (int m = 1; m < 16; m <<= 1) {
                float obv = __shfl_xor(b, m, 64);
                int   okv = __shfl_xor(k, m, 64);
                if (obv < b || (obv == b && okv < k)) { b = obv; k = okv; }
            }
            if (lc == 0) codebuf[w][rt * 16 + lq * 4 + j] = k;   // D row = lq*4+j
        }

    // ---- emit codes + int counts (within-wave LDS dep only; no barrier) ----
    if (l < 32) {
        int code = codebuf[w][l];
        size_t rowg = (size_t)waveRow + l;
        codes_i[rowg] = code;
        codes_f[rowg] = (float)code;
        atomicAdd(&counts[code], 1);
    }
}

// ---------------- kernel: scan counts -> offsets/cursor + cluster-size + n + loss=0 ----
__global__ void k_scan(const int* __restrict__ counts,
                       int* __restrict__ offsets, int* __restrict__ cursor,
                       const float* __restrict__ ema_cs, float* __restrict__ ncs_out,
                       float* __restrict__ n_out, double* __restrict__ lossp) {
    __shared__ int   part[256];
    __shared__ float fpart[256];
    int tid = threadIdx.x;
    if (tid == 0) *lossp = 0.0;
    int base = tid * 16;
    int loc[16];
    int s = 0;
    float fs = 0.f;
    #pragma unroll
    for (int j = 0; j < 16; ++j) {
        int cnt = counts[base + j];
        loc[j] = s; s += cnt;
        float v = 0.99f * ema_cs[base + j] + 0.01f * (float)cnt;
        ncs_out[base + j] = v;
        fs += v;
    }
    part[tid] = s;
    fpart[tid] = fs;
    __syncthreads();
    for (int off = 1; off < 256; off <<= 1) {
        int v = (tid >= off) ? part[tid - off] : 0;
        __syncthreads();
        part[tid] += v;
        __syncthreads();
    }
    int excl = part[tid] - s;
    #pragma unroll
    for (int j = 0; j < 16; ++j) {
        int o = excl + loc[j];
        offsets[base + j] = o;
        cursor[base + j]  = o;
    }
    if (tid == 255) offsets[KC] = excl + s;
    for (int m = 128; m > 0; m >>= 1) {
        if (tid < m) fpart[tid] += fpart[tid + m];
        __syncthreads();
    }
    if (tid == 0) n_out[0] = fpart[0];
}

// ---------------- kernel: scatter row indices into code-sorted order ----------------
__global__ void k_scatteridx(const int* __restrict__ codes_i,
                             int* __restrict__ cursor, int* __restrict__ sorted_rows) {
    int r = blockIdx.x * 256 + threadIdx.x;
    if (r < NROWS) {
        int c = codes_i[r];
        int p = atomicAdd(&cursor[c], 1);
        sorted_rows[p] = r;
    }
}

// ---------------- kernel: segmented sum -> dw (one block per code, coalesced) ----------------
__global__ __launch_bounds__(64) void k_dwsum(
        const float* __restrict__ z, const int* __restrict__ offsets,
        const int* __restrict__ sorted_rows, float* __restrict__ dw) {
    int k = blockIdx.x, tid = threadIdx.x;
    int beg = offsets[k], end = offsets[k + 1];
    float a0 = 0.f, a1 = 0.f, a2 = 0.f, a3 = 0.f;
    int i = beg;
    for (; i + 3 < end; i += 4) {
        int r0 = sorted_rows[i], r1 = sorted_rows[i + 1];
        int r2 = sorted_rows[i + 2], r3 = sorted_rows[i + 3];
        a0 += z[(size_t)r0 * DIM + tid];
        a1 += z[(size_t)r1 * DIM + tid];
        a2 += z[(size_t)r2 * DIM + tid];
        a3 += z[(size_t)r3 * DIM + tid];
    }
    for (; i < end; ++i) a0 += z[(size_t)sorted_rows[i] * DIM + tid];
    dw[(size_t)k * DIM + tid] = (a0 + a1) + (a2 + a3);
}

// ---------------- kernel: new_ema_w + new_embedding ----------------
__global__ void k_update(const float* __restrict__ ema_w, const float* __restrict__ dw,
                         const float* __restrict__ ncs, const float* __restrict__ nptr,
                         float* __restrict__ new_ema_w_out, float* __restrict__ new_emb_out) {
    int idx = blockIdx.x * 256 + threadIdx.x;
    float n = nptr[0];
    int k = idx >> 6;
    float nw = 0.99f * ema_w[idx] + 0.01f * dw[idx];
    float cs = (ncs[k] + 1e-5f) / (n + 4096.0f * 1e-5f) * n;
    new_ema_w_out[idx] = nw;
    new_emb_out[idx] = nw / cs;
}

// ---------------- kernel: quantize + straight-through + loss ----------------
__global__ __launch_bounds__(256) void k_quant(
        const float* __restrict__ z, const float* __restrict__ new_emb,
        const int* __restrict__ codes, float* __restrict__ zq_out,
        double* __restrict__ loss_acc) {
    __shared__ double red[256];
    const int nvec = NELEM / 4;
    int t = blockIdx.x * 256 + threadIdx.x;
    int stride = gridDim.x * 256;
    double ls = 0.0;
    for (int v = t; v < nvec; v += stride) {
        int e0 = v * 4;
        int n  = e0 >> 6;
        int d0 = e0 & 63;
        int code = codes[n];
        float4 zq = *(const float4*)&new_emb[(size_t)code * DIM + d0];
        float4 zv = *(const float4*)&z[e0];
        float dx = zq.x - zv.x, dy = zq.y - zv.y, dz = zq.z - zv.z, dw4 = zq.w - zv.w;
        float4 o;
        o.x = zv.x + dx; o.y = zv.y + dy; o.z = zv.z + dz; o.w = zv.w + dw4;
        *(float4*)&zq_out[e0] = o;
        ls += (double)(dx * dx) + (double)(dy * dy) + (double)(dz * dz) + (double)(dw4 * dw4);
    }
    red[threadIdx.x] = ls;
    __syncthreads();
    for (int m = 128; m > 0; m >>= 1) {
        if (threadIdx.x < m) red[threadIdx.x] += red[threadIdx.x + m];
        __syncthreads();
    }
    if (threadIdx.x == 0) atomicAdd(loss_acc, red[0]);
}

__global__ void k_loss(const double* __restrict__ loss_acc, float* __restrict__ out0) {
    out0[0] = (float)(0.25 * (loss_acc[0] / (double)NELEM));
}

// ---------------- launcher ----------------
extern "C" void kernel_launch(void* const* d_in, const int* in_sizes, int n_in,
                              void* d_out, int out_size, void* d_ws, size_t ws_size,
                              hipStream_t stream) {
    const float* z      = (const float*)d_in[0];
    const float* emb    = (const float*)d_in[1];
    const float* ema_cs = (const float*)d_in[2];
    const float* ema_w  = (const float*)d_in[3];
    float* out = (float*)d_out;
    char*  ws  = (char*)d_ws;

    int*    codes_i = (int*)(ws + WS_CODES);
    int*    counts  = (int*)(ws + WS_COUNTS);
    int*    offsets = (int*)(ws + WS_OFFS);
    int*    cursor  = (int*)(ws + WS_CURSOR);
    int*    sorted  = (int*)(ws + WS_SORTED);
    float*  dw      = (float*)(ws + WS_DW);
    float*  e2h     = (float*)(ws + WS_E2);
    float*  nptr    = (float*)(ws + WS_N);
    double* lossp   = (double*)(ws + WS_LOSSD);
    char*   emb_pk  = ws + WS_EMBPK;

    k_prep<<<(KC * 8) / 256, 256, 0, stream>>>(emb, emb_pk, e2h, counts);
    k_argmin4<<<NROWS / 128, 256, 0, stream>>>(z, emb_pk, e2h, codes_i,
                                               out + OUT_CODES, counts);
    k_scan<<<1, 256, 0, stream>>>(counts, offsets, cursor, ema_cs,
                                  out + OUT_NCS, nptr, lossp);
    k_scatteridx<<<(NROWS + 255) / 256, 256, 0, stream>>>(codes_i, cursor, sorted);
    k_dwsum<<<KC, 64, 0, stream>>>(z, offsets, sorted, dw);
    k_update<<<(KC * DIM) / 256, 256, 0, stream>>>(ema_w, dw, out + OUT_NCS, nptr,
                                                   out + OUT_NEW, out + OUT_EMB);
    k_quant<<<1152, 256, 0, stream>>>(z, out + OUT_EMB, codes_i,
                                      out + OUT_ZQ, lossp);
    k_loss<<<1, 1, 0, stream>>>(lossp, out + OUT_LOSS);
}

// Round 6
// 186.491 us; speedup vs baseline: 3.6459x; 1.1804x over previous
//
#include <hip/hip_runtime.h>

// ---------------- problem constants ----------------
constexpr int KC    = 4096;      // NUM_EMBEDDINGS
constexpr int DIM   = 64;        // EMBEDDING_DIM
constexpr int NROWS = 73728;     // 128*24*1536/64
constexpr int NELEM = 4718592;   // 128*24*1536

typedef _Float16 f16x8 __attribute__((ext_vector_type(8)));
typedef float    f32x4 __attribute__((ext_vector_type(4)));

// ---------------- output layout (floats) ----------------
constexpr size_t OUT_LOSS  = 0;                               // 1
constexpr size_t OUT_ZQ    = 1;                               // NELEM
constexpr size_t OUT_CODES = 1 + (size_t)NELEM;               // NROWS
constexpr size_t OUT_EMB   = OUT_CODES + (size_t)NROWS;       // KC*DIM
constexpr size_t OUT_NCS   = OUT_EMB + (size_t)KC * DIM;      // KC
constexpr size_t OUT_NEW   = OUT_NCS + (size_t)KC;            // KC*DIM

// ---------------- workspace layout (bytes) ----------------
constexpr size_t alignup(size_t x, size_t a) { return (x + a - 1) & ~(a - 1); }
constexpr size_t WS_CODES  = 0;                                            // int[NROWS]
constexpr size_t WS_COUNTS = WS_CODES + sizeof(int) * (size_t)NROWS;       // int[KC]
constexpr size_t WS_OFFS   = WS_COUNTS + sizeof(int) * (size_t)KC;         // int[KC+1]
constexpr size_t WS_CURSOR = alignup(WS_OFFS + sizeof(int) * (KC + 1), 16);// int[KC]
constexpr size_t WS_SORTED = WS_CURSOR + sizeof(int) * (size_t)KC;         // int[NROWS]
constexpr size_t WS_E2     = alignup(WS_SORTED + sizeof(int) * (size_t)NROWS, 16); // float[KC]
constexpr size_t WS_N      = WS_E2 + sizeof(float) * (size_t)KC;           // float[1]
constexpr size_t WS_LOSSD  = alignup(WS_N + sizeof(float), 8);             // double[1]
constexpr size_t WS_EMBPK  = alignup(WS_LOSSD + 8, 16);                    // 1 MB packed emb

// ---------------- kernel: pack emb -> fp16 hi/lo B-frags + e2s + zero counts ----------
// group g (16 codes) at g*4096; frag f (0:hi-h0, 1:hi-h1, 2:lo-h0, 3:lo-h1) at +f*1024;
// lane l at +l*16 holds e[g*16 + (l&15)][h*32 + (l>>4)*8 .. +8].
// e2s[k] = 2^11 * 0.5 * sum(e[k]^2)  (scaled-dist C-init). Also zeroes counts.
__global__ void k_prep(const float* __restrict__ emb, char* __restrict__ emb_pk,
                       float* __restrict__ e2s, int* __restrict__ counts) {
    if (threadIdx.x < 32) counts[blockIdx.x * 32 + threadIdx.x] = 0;
    int t = blockIdx.x * 256 + threadIdx.x;   // 0 .. 32767
    int c = t >> 3, q = t & 7;                // code, d-chunk of 8
    const float* ep = emb + (size_t)c * DIM + q * 8;
    f16x8 hv, lv;
    float s = 0.f;
    #pragma unroll
    for (int e = 0; e < 8; ++e) {
        float x = ep[e];
        _Float16 h = (_Float16)x;
        float r = x - (float)h;
        hv[e] = h;                          // raw e_hi
        lv[e] = (_Float16)(r * 2048.0f);    // 2^11 * e_lo
        s = fmaf(x, x, s);
    }
    s += __shfl_xor(s, 1, 64);
    s += __shfl_xor(s, 2, 64);
    s += __shfl_xor(s, 4, 64);
    if (q == 0) e2s[c] = 1024.0f * s;       // 2^11 * (0.5 * sum e^2)
    int g = c >> 4, lc = c & 15;
    int h = q >> 2, lq = q & 3;
    int lane = lq * 16 + lc;
    char* base = emb_pk + (size_t)g * 4096 + lane * 16;
    *(f16x8*)(base + h * 1024)       = hv;
    *(f16x8*)(base + (2 + h) * 1024) = lv;
}

// ---------------- kernel: MFMA distance argmin (single-chain scaled split) ----------------
// 768 blocks x 192 threads (3 waves) = exactly 3 blocks/CU. Each wave owns 32 rows,
// sweeps all 4096 codes in 16-code groups, 4-deep register pipeline, no __syncthreads.
// dist' = 2^11*(e2h - z.e) accumulated in ONE chain of 6 MFMAs:
//   C-init = 2^11 e2h;  (-2^11 z_hi).e_hi  (-z_hi).(2^11 e_lo)  (-2^11 z_lo).e_hi
__global__ __launch_bounds__(192, 3) void k_argmin5(
        const float* __restrict__ z, const char* __restrict__ emb_pk,
        const float* __restrict__ e2s,
        int* __restrict__ codes_i, float* __restrict__ codes_f,
        int* __restrict__ counts) {
    __shared__ int codebuf[3][32];

    const int tid = threadIdx.x;
    const int l   = tid & 63;
    const int w   = tid >> 6;
    const int lc  = l & 15;
    const int lq  = l >> 4;
    const int waveRow = blockIdx.x * 96 + w * 32;

    // ---- A fragments: 32 z-rows -> three negated scaled fp16 forms ----
    f16x8 ah2k[2][2], ahr[2][2], al2k[2][2];
    #pragma unroll
    for (int rt = 0; rt < 2; ++rt)
        #pragma unroll
        for (int h = 0; h < 2; ++h) {
            const float* zp = z + (size_t)(waveRow + rt * 16 + lc) * DIM + h * 32 + lq * 8;
            float4 x0 = *(const float4*)zp;
            float4 x1 = *(const float4*)(zp + 4);
            float xs[8] = {x0.x, x0.y, x0.z, x0.w, x1.x, x1.y, x1.z, x1.w};
            #pragma unroll
            for (int e = 0; e < 8; ++e) {
                _Float16 hh = (_Float16)xs[e];
                float rr = xs[e] - (float)hh;
                ahr[rt][h][e]  = -hh;
                ah2k[rt][h][e] = (_Float16)(-2048.0f * (float)hh);   // exact pow2 scale
                al2k[rt][h][e] = -(_Float16)(rr * 2048.0f);
            }
        }

    float best[2][4];
    int   bestk[2][4];
    #pragma unroll
    for (int rt = 0; rt < 2; ++rt)
        #pragma unroll
        for (int j = 0; j < 4; ++j) { best[rt][j] = INFINITY; bestk[rt][j] = 0; }

    const char* pk = emb_pk + l * 16;

#define LOADG(EC, B0, B1, B2, B3, G) {                                   \
        const char* p_ = pk + (size_t)(G) * 4096;                        \
        B0 = *(const f16x8*)(p_);                                        \
        B1 = *(const f16x8*)(p_ + 1024);                                 \
        B2 = *(const f16x8*)(p_ + 2048);                                 \
        B3 = *(const f16x8*)(p_ + 3072);                                 \
        EC = e2s[(G) * 16 + lc]; }

#define COMPUTE(B0, B1, B2, B3, EC, G) {                                          \
        _Pragma("unroll")                                                         \
        for (int rt = 0; rt < 2; ++rt) {                                          \
            f32x4 acc; acc[0] = EC; acc[1] = EC; acc[2] = EC; acc[3] = EC;        \
            acc = __builtin_amdgcn_mfma_f32_16x16x32_f16(ah2k[rt][0], B0, acc, 0, 0, 0); \
            acc = __builtin_amdgcn_mfma_f32_16x16x32_f16(ah2k[rt][1], B1, acc, 0, 0, 0); \
            acc = __builtin_amdgcn_mfma_f32_16x16x32_f16(ahr[rt][0],  B2, acc, 0, 0, 0); \
            acc = __builtin_amdgcn_mfma_f32_16x16x32_f16(ahr[rt][1],  B3, acc, 0, 0, 0); \
            acc = __builtin_amdgcn_mfma_f32_16x16x32_f16(al2k[rt][0], B0, acc, 0, 0, 0); \
            acc = __builtin_amdgcn_mfma_f32_16x16x32_f16(al2k[rt][1], B1, acc, 0, 0, 0); \
            _Pragma("unroll")                                                     \
            for (int j = 0; j < 4; ++j) {                                         \
                if (acc[j] < best[rt][j]) { best[rt][j] = acc[j]; bestk[rt][j] = (G) * 16 + lc; } \
            }                                                                     \
        } }

    {
        f16x8 A0, A1, A2, A3, B0, B1, B2, B3, C0, C1, C2, C3, D0, D1, D2, D3;
        float eA, eB, eC, eD;
        LOADG(eA, A0, A1, A2, A3, 0);
        LOADG(eB, B0, B1, B2, B3, 1);
        LOADG(eC, C0, C1, C2, C3, 2);
        for (int g = 0; g < 252; g += 4) {
            LOADG(eD, D0, D1, D2, D3, g + 3);
            COMPUTE(A0, A1, A2, A3, eA, g);
            LOADG(eA, A0, A1, A2, A3, g + 4);
            COMPUTE(B0, B1, B2, B3, eB, g + 1);
            LOADG(eB, B0, B1, B2, B3, g + 5);
            COMPUTE(C0, C1, C2, C3, eC, g + 2);
            LOADG(eC, C0, C1, C2, C3, g + 6);
            COMPUTE(D0, D1, D2, D3, eD, g + 3);
        }
        // loop exits having loaded A<-252, B<-253, C<-254
        LOADG(eD, D0, D1, D2, D3, 255);
        COMPUTE(A0, A1, A2, A3, eA, 252);
        COMPUTE(B0, B1, B2, B3, eB, 253);
        COMPUTE(C0, C1, C2, C3, eC, 254);
        COMPUTE(D0, D1, D2, D3, eD, 255);
    }
#undef LOADG
#undef COMPUTE

    // ---- butterfly argmin reduce over the 16 lanes of each lq-group ----
    #pragma unroll
    for (int rt = 0; rt < 2; ++rt)
        #pragma unroll
        for (int j = 0; j < 4; ++j) {
            float b = best[rt][j];
            int   k = bestk[rt][j];
            #pragma unroll
            for (int m = 1; m < 16; m <<= 1) {
                float obv = __shfl_xor(b, m, 64);
                int   okv = __shfl_xor(k, m, 64);
                if (obv < b || (obv == b && okv < k)) { b = obv; k = okv; }
            }
            if (lc == 0) codebuf[w][rt * 16 + lq * 4 + j] = k;   // D row = lq*4+j
        }

    // ---- emit codes + int counts (within-wave LDS dep only; no barrier) ----
    if (l < 32) {
        int code = codebuf[w][l];
        size_t rowg = (size_t)waveRow + l;
        codes_i[rowg] = code;
        codes_f[rowg] = (float)code;
        atomicAdd(&counts[code], 1);
    }
}

// ---------------- kernel: scan counts -> offsets/cursor + cluster-size + n + loss=0 ----
__global__ void k_scan(const int* __restrict__ counts,
                       int* __restrict__ offsets, int* __restrict__ cursor,
                       const float* __restrict__ ema_cs, float* __restrict__ ncs_out,
                       float* __restrict__ n_out, double* __restrict__ lossp) {
    __shared__ int   part[256];
    __shared__ float fpart[256];
    int tid = threadIdx.x;
    if (tid == 0) *lossp = 0.0;
    int base = tid * 16;
    int loc[16];
    int s = 0;
    float fs = 0.f;
    #pragma unroll
    for (int j = 0; j < 16; ++j) {
        int cnt = counts[base + j];
        loc[j] = s; s += cnt;
        float v = 0.99f * ema_cs[base + j] + 0.01f * (float)cnt;
        ncs_out[base + j] = v;
        fs += v;
    }
    part[tid] = s;
    fpart[tid] = fs;
    __syncthreads();
    for (int off = 1; off < 256; off <<= 1) {
        int v = (tid >= off) ? part[tid - off] : 0;
        __syncthreads();
        part[tid] += v;
        __syncthreads();
    }
    int excl = part[tid] - s;
    #pragma unroll
    for (int j = 0; j < 16; ++j) {
        int o = excl + loc[j];
        offsets[base + j] = o;
        cursor[base + j]  = o;
    }
    if (tid == 255) offsets[KC] = excl + s;
    for (int m = 128; m > 0; m >>= 1) {
        if (tid < m) fpart[tid] += fpart[tid + m];
        __syncthreads();
    }
    if (tid == 0) n_out[0] = fpart[0];
}

// ---------------- kernel: scatter row indices into code-sorted order ----------------
__global__ void k_scatteridx(const int* __restrict__ codes_i,
                             int* __restrict__ cursor, int* __restrict__ sorted_rows) {
    int r = blockIdx.x * 256 + threadIdx.x;
    if (r < NROWS) {
        int c = codes_i[r];
        int p = atomicAdd(&cursor[c], 1);
        sorted_rows[p] = r;
    }
}

// ---------------- kernel: segmented sum -> dw, fused EMA-w + new embedding ----------------
__global__ __launch_bounds__(64) void k_dwsum(
        const float* __restrict__ z, const int* __restrict__ offsets,
        const int* __restrict__ sorted_rows, const float* __restrict__ ema_w,
        const float* __restrict__ ncs, const float* __restrict__ nptr,
        float* __restrict__ new_ema_w_out, float* __restrict__ new_emb_out) {
    int k = blockIdx.x, tid = threadIdx.x;
    int beg = offsets[k], end = offsets[k + 1];
    float a0 = 0.f, a1 = 0.f, a2 = 0.f, a3 = 0.f;
    int i = beg;
    for (; i + 3 < end; i += 4) {
        int r0 = sorted_rows[i], r1 = sorted_rows[i + 1];
        int r2 = sorted_rows[i + 2], r3 = sorted_rows[i + 3];
        a0 += z[(size_t)r0 * DIM + tid];
        a1 += z[(size_t)r1 * DIM + tid];
        a2 += z[(size_t)r2 * DIM + tid];
        a3 += z[(size_t)r3 * DIM + tid];
    }
    for (; i < end; ++i) a0 += z[(size_t)sorted_rows[i] * DIM + tid];
    float dwv = (a0 + a1) + (a2 + a3);
    size_t idx = (size_t)k * DIM + tid;
    float n = nptr[0];
    float nw = 0.99f * ema_w[idx] + 0.01f * dwv;
    float cs = (ncs[k] + 1e-5f) / (n + 4096.0f * 1e-5f) * n;
    new_ema_w_out[idx] = nw;
    new_emb_out[idx] = nw / cs;
}

// ---------------- kernel: quantize + straight-through + loss ----------------
__global__ __launch_bounds__(256) void k_quant(
        const float* __restrict__ z, const float* __restrict__ new_emb,
        const int* __restrict__ codes, float* __restrict__ zq_out,
        double* __restrict__ loss_acc) {
    __shared__ double red[256];
    const int nvec = NELEM / 4;
    int t = blockIdx.x * 256 + threadIdx.x;
    int stride = gridDim.x * 256;
    double ls = 0.0;
    for (int v = t; v < nvec; v += stride) {
        int e0 = v * 4;
        int n  = e0 >> 6;
        int d0 = e0 & 63;
        int code = codes[n];
        float4 zq = *(const float4*)&new_emb[(size_t)code * DIM + d0];
        float4 zv = *(const float4*)&z[e0];
        float dx = zq.x - zv.x, dy = zq.y - zv.y, dz = zq.z - zv.z, dw4 = zq.w - zv.w;
        float4 o;
        o.x = zv.x + dx; o.y = zv.y + dy; o.z = zv.z + dz; o.w = zv.w + dw4;
        *(float4*)&zq_out[e0] = o;
        ls += (double)(dx * dx) + (double)(dy * dy) + (double)(dz * dz) + (double)(dw4 * dw4);
    }
    red[threadIdx.x] = ls;
    __syncthreads();
    for (int m = 128; m > 0; m >>= 1) {
        if (threadIdx.x < m) red[threadIdx.x] += red[threadIdx.x + m];
        __syncthreads();
    }
    if (threadIdx.x == 0) atomicAdd(loss_acc, red[0]);
}

__global__ void k_loss(const double* __restrict__ loss_acc, float* __restrict__ out0) {
    out0[0] = (float)(0.25 * (loss_acc[0] / (double)NELEM));
}

// ---------------- launcher ----------------
extern "C" void kernel_launch(void* const* d_in, const int* in_sizes, int n_in,
                              void* d_out, int out_size, void* d_ws, size_t ws_size,
                              hipStream_t stream) {
    const float* z      = (const float*)d_in[0];
    const float* emb    = (const float*)d_in[1];
    const float* ema_cs = (const float*)d_in[2];
    const float* ema_w  = (const float*)d_in[3];
    float* out = (float*)d_out;
    char*  ws  = (char*)d_ws;

    int*    codes_i = (int*)(ws + WS_CODES);
    int*    counts  = (int*)(ws + WS_COUNTS);
    int*    offsets = (int*)(ws + WS_OFFS);
    int*    cursor  = (int*)(ws + WS_CURSOR);
    int*    sorted  = (int*)(ws + WS_SORTED);
    float*  e2s     = (float*)(ws + WS_E2);
    float*  nptr    = (float*)(ws + WS_N);
    double* lossp   = (double*)(ws + WS_LOSSD);
    char*   emb_pk  = ws + WS_EMBPK;

    k_prep<<<(KC * 8) / 256, 256, 0, stream>>>(emb, emb_pk, e2s, counts);
    k_argmin5<<<NROWS / 96, 192, 0, stream>>>(z, emb_pk, e2s, codes_i,
                                              out + OUT_CODES, counts);
    k_scan<<<1, 256, 0, stream>>>(counts, offsets, cursor, ema_cs,
                                  out + OUT_NCS, nptr, lossp);
    k_scatteridx<<<(NROWS + 255) / 256, 256, 0, stream>>>(codes_i, cursor, sorted);
    k_dwsum<<<KC, 64, 0, stream>>>(z, offsets, sorted, ema_w,
                                   out + OUT_NCS, nptr, out + OUT_NEW, out + OUT_EMB);
    k_quant<<<1152, 256, 0, stream>>>(z, out + OUT_EMB, codes_i,
                                      out + OUT_ZQ, lossp);
    k_loss<<<1, 1, 0, stream>>>(lossp, out + OUT_LOSS);
}

// Round 7
// 180.354 us; speedup vs baseline: 3.7699x; 1.0340x over previous
//
#include <hip/hip_runtime.h>

// ---------------- problem constants ----------------
constexpr int KC    = 4096;      // NUM_EMBEDDINGS
constexpr int DIM   = 64;        // EMBEDDING_DIM
constexpr int NROWS = 73728;     // 128*24*1536/64
constexpr int NELEM = 4718592;   // 128*24*1536
constexpr int GSTRIDE = 4160;    // per-16-code group block: 64B e2s + 4KB frags

typedef _Float16 f16x8 __attribute__((ext_vector_type(8)));
typedef float    f32x4 __attribute__((ext_vector_type(4)));

// ---------------- output layout (floats) ----------------
constexpr size_t OUT_LOSS  = 0;                               // 1
constexpr size_t OUT_ZQ    = 1;                               // NELEM
constexpr size_t OUT_CODES = 1 + (size_t)NELEM;               // NROWS
constexpr size_t OUT_EMB   = OUT_CODES + (size_t)NROWS;       // KC*DIM
constexpr size_t OUT_NCS   = OUT_EMB + (size_t)KC * DIM;      // KC
constexpr size_t OUT_NEW   = OUT_NCS + (size_t)KC;            // KC*DIM

// ---------------- workspace layout (bytes) ----------------
constexpr size_t alignup(size_t x, size_t a) { return (x + a - 1) & ~(a - 1); }
constexpr size_t WS_CODES  = 0;                                            // int[NROWS]
constexpr size_t WS_COUNTS = WS_CODES + sizeof(int) * (size_t)NROWS;       // int[KC]
constexpr size_t WS_OFFS   = WS_COUNTS + sizeof(int) * (size_t)KC;         // int[KC+1]
constexpr size_t WS_CURSOR = alignup(WS_OFFS + sizeof(int) * (KC + 1), 16);// int[KC]
constexpr size_t WS_SORTED = WS_CURSOR + sizeof(int) * (size_t)KC;         // int[NROWS]
constexpr size_t WS_N      = alignup(WS_SORTED + sizeof(int) * (size_t)NROWS, 16); // float[1]
constexpr size_t WS_LOSSD  = alignup(WS_N + sizeof(float), 8);             // double[1]
constexpr size_t WS_EMBPK  = alignup(WS_LOSSD + 8, 64);                    // 256*4160 + margin

// ---------------- kernel: pack emb -> group blocks {e2s[16], hi/lo frags} + zero counts ----
// group g at g*4160: [0,64) = e2s floats (2^11 * 0.5*||e||^2 for the 16 codes);
// [64,4160) = frag f (0:hi-h0,1:hi-h1,2:lo-h0,3:lo-h1) at 64+f*1024, lane l at +l*16:
// e[g*16+(l&15)][h*32 + (l>>4)*8 .. +8].
__global__ void k_prep(const float* __restrict__ emb, char* __restrict__ emb_pk,
                       int* __restrict__ counts) {
    if (threadIdx.x < 32) counts[blockIdx.x * 32 + threadIdx.x] = 0;
    int t = blockIdx.x * 256 + threadIdx.x;   // 0 .. 32767
    int c = t >> 3, q = t & 7;                // code, d-chunk of 8
    const float* ep = emb + (size_t)c * DIM + q * 8;
    f16x8 hv, lv;
    float s = 0.f;
    #pragma unroll
    for (int e = 0; e < 8; ++e) {
        float x = ep[e];
        _Float16 h = (_Float16)x;
        float r = x - (float)h;
        hv[e] = h;                          // raw e_hi
        lv[e] = (_Float16)(r * 2048.0f);    // 2^11 * e_lo
        s = fmaf(x, x, s);
    }
    s += __shfl_xor(s, 1, 64);
    s += __shfl_xor(s, 2, 64);
    s += __shfl_xor(s, 4, 64);
    int g = c >> 4, lc = c & 15;
    int h = q >> 2, lq = q & 3;
    int lane = lq * 16 + lc;
    char* gbase = emb_pk + (size_t)g * GSTRIDE;
    if (q == 0) *(float*)(gbase + lc * 4) = 1024.0f * s;   // 2^11*(0.5*sum e^2)
    char* base = gbase + 64 + lane * 16;
    *(f16x8*)(base + h * 1024)       = hv;
    *(f16x8*)(base + (2 + h) * 1024) = lv;
}

// ---------------- kernel: MFMA distance argmin, counted-vmcnt register pipeline ----------
// 768 blocks x 192 threads (3 waves) = 3 blocks/CU, 9 waves/CU. Wave owns 32 rows,
// sweeps all 256 groups; 4 asm-pinned load stages in flight (20 loads), wait vmcnt(15)
// per group. No __syncthreads. dist' = 2^11*(0.5||e||^2 - z.e), one 6-MFMA chain.
__global__ __launch_bounds__(192, 3) void k_argmin6(
        const float* __restrict__ z, const char* __restrict__ emb_pk,
        int* __restrict__ codes_i, float* __restrict__ codes_f,
        int* __restrict__ counts) {
    __shared__ int codebuf[3][32];

    const int tid = threadIdx.x;
    const int l   = tid & 63;
    const int w   = tid >> 6;
    const int lc  = l & 15;
    const int lq  = l >> 4;
    const int waveRow = blockIdx.x * 96 + w * 32;

    // ---- A fragments: 32 z-rows -> three negated scaled fp16 forms ----
    f16x8 ah2k[2][2], ahr[2][2], al2k[2][2];
    #pragma unroll
    for (int rt = 0; rt < 2; ++rt)
        #pragma unroll
        for (int h = 0; h < 2; ++h) {
            const float* zp = z + (size_t)(waveRow + rt * 16 + lc) * DIM + h * 32 + lq * 8;
            float4 x0 = *(const float4*)zp;
            float4 x1 = *(const float4*)(zp + 4);
            float xs[8] = {x0.x, x0.y, x0.z, x0.w, x1.x, x1.y, x1.z, x1.w};
            #pragma unroll
            for (int e = 0; e < 8; ++e) {
                _Float16 hh = (_Float16)xs[e];
                float rr = xs[e] - (float)hh;
                ahr[rt][h][e]  = -hh;
                ah2k[rt][h][e] = (_Float16)(-2048.0f * (float)hh);   // exact pow2 scale
                al2k[rt][h][e] = -(_Float16)(rr * 2048.0f);
            }
        }

    float best[2][4];
    int   bestg[2][4];
    #pragma unroll
    for (int rt = 0; rt < 2; ++rt)
        #pragma unroll
        for (int j = 0; j < 4; ++j) { best[rt][j] = INFINITY; bestg[rt][j] = 0; }

    const unsigned long long pkb = (unsigned long long)emb_pk;
    unsigned voffA = 64 + l * 16;   // fragment stream
    unsigned voffB = lc * 4;        // e2s stream

    f16x8 b00, b01, b02, b03, b10, b11, b12, b13;
    f16x8 b20, b21, b22, b23, b30, b31, b32, b33;
    float e0, e1, e2v, e3;

#define ISSUE(B0, B1, B2, B3, EV)                                                        \
    asm volatile("global_load_dword %0, %1, %2"             : "=v"(EV) : "v"(voffB), "s"(pkb)); \
    asm volatile("global_load_dwordx4 %0, %1, %2"             : "=v"(B0) : "v"(voffA), "s"(pkb)); \
    asm volatile("global_load_dwordx4 %0, %1, %2 offset:1024" : "=v"(B1) : "v"(voffA), "s"(pkb)); \
    asm volatile("global_load_dwordx4 %0, %1, %2 offset:2048" : "=v"(B2) : "v"(voffA), "s"(pkb)); \
    asm volatile("global_load_dwordx4 %0, %1, %2 offset:3072" : "=v"(B3) : "v"(voffA), "s"(pkb)); \
    voffA += GSTRIDE; voffB += GSTRIDE;

#define WAITP                                                \
    asm volatile("s_waitcnt vmcnt(15)" ::: "memory");        \
    __builtin_amdgcn_sched_barrier(0);

#define COMP(B0, B1, B2, B3, EV, G) {                                             \
        f32x4 ci; ci[0] = EV; ci[1] = EV; ci[2] = EV; ci[3] = EV;                 \
        _Pragma("unroll")                                                         \
        for (int rt = 0; rt < 2; ++rt) {                                          \
            f32x4 acc = __builtin_amdgcn_mfma_f32_16x16x32_f16(ah2k[rt][0], B0, ci, 0, 0, 0); \
            acc = __builtin_amdgcn_mfma_f32_16x16x32_f16(ah2k[rt][1], B1, acc, 0, 0, 0);      \
            acc = __builtin_amdgcn_mfma_f32_16x16x32_f16(ahr[rt][0],  B2, acc, 0, 0, 0);      \
            acc = __builtin_amdgcn_mfma_f32_16x16x32_f16(ahr[rt][1],  B3, acc, 0, 0, 0);      \
            acc = __builtin_amdgcn_mfma_f32_16x16x32_f16(al2k[rt][0], B0, acc, 0, 0, 0);      \
            acc = __builtin_amdgcn_mfma_f32_16x16x32_f16(al2k[rt][1], B1, acc, 0, 0, 0);      \
            _Pragma("unroll")                                                     \
            for (int j = 0; j < 4; ++j) {                                         \
                if (acc[j] < best[rt][j]) { best[rt][j] = acc[j]; bestg[rt][j] = (G); } \
            }                                                                     \
        } }

    __builtin_amdgcn_sched_barrier(0);   // keep A-prep (and its waits) above the asm stream
    ISSUE(b00, b01, b02, b03, e0)        // G0
    ISSUE(b10, b11, b12, b13, e1)        // G1
    ISSUE(b20, b21, b22, b23, e2v)       // G2
    ISSUE(b30, b31, b32, b33, e3)        // G3

    for (int g = 0; g < 256; g += 4) {
        WAITP  COMP(b00, b01, b02, b03, e0,  g)      ISSUE(b00, b01, b02, b03, e0)
        WAITP  COMP(b10, b11, b12, b13, e1,  g + 1)  ISSUE(b10, b11, b12, b13, e1)
        WAITP  COMP(b20, b21, b22, b23, e2v, g + 2)  ISSUE(b20, b21, b22, b23, e2v)
        WAITP  COMP(b30, b31, b32, b33, e3,  g + 3)  ISSUE(b30, b31, b32, b33, e3)
    }
    asm volatile("s_waitcnt vmcnt(0)" ::: "memory");   // drain dummy tail loads
    __builtin_amdgcn_sched_barrier(0);
#undef ISSUE
#undef WAITP
#undef COMP

    // ---- butterfly argmin reduce over the 16 lanes of each lq-group ----
    #pragma unroll
    for (int rt = 0; rt < 2; ++rt)
        #pragma unroll
        for (int j = 0; j < 4; ++j) {
            float b = best[rt][j];
            int   k = bestg[rt][j] * 16 + lc;
            #pragma unroll
            for (int m = 1; m < 16; m <<= 1) {
                float obv = __shfl_xor(b, m, 64);
                int   okv = __shfl_xor(k, m, 64);
                if (obv < b || (obv == b && okv < k)) { b = obv; k = okv; }
            }
            if (lc == 0) codebuf[w][rt * 16 + lq * 4 + j] = k;   // D row = lq*4+j
        }

    // ---- emit codes + int counts (within-wave LDS dep only; no barrier) ----
    if (l < 32) {
        int code = codebuf[w][l];
        size_t rowg = (size_t)waveRow + l;
        codes_i[rowg] = code;
        codes_f[rowg] = (float)code;
        atomicAdd(&counts[code], 1);
    }
}

// ---------------- kernel: scan counts -> offsets/cursor + cluster-size + n + loss=0 ----
__global__ void k_scan(const int* __restrict__ counts,
                       int* __restrict__ offsets, int* __restrict__ cursor,
                       const float* __restrict__ ema_cs, float* __restrict__ ncs_out,
                       float* __restrict__ n_out, double* __restrict__ lossp) {
    __shared__ int   part[256];
    __shared__ float fpart[256];
    int tid = threadIdx.x;
    if (tid == 0) *lossp = 0.0;
    int base = tid * 16;
    int loc[16];
    int s = 0;
    float fs = 0.f;
    #pragma unroll
    for (int j = 0; j < 16; ++j) {
        int cnt = counts[base + j];
        loc[j] = s; s += cnt;
        float v = 0.99f * ema_cs[base + j] + 0.01f * (float)cnt;
        ncs_out[base + j] = v;
        fs += v;
    }
    part[tid] = s;
    fpart[tid] = fs;
    __syncthreads();
    for (int off = 1; off < 256; off <<= 1) {
        int v = (tid >= off) ? part[tid - off] : 0;
        __syncthreads();
        part[tid] += v;
        __syncthreads();
    }
    int excl = part[tid] - s;
    #pragma unroll
    for (int j = 0; j < 16; ++j) {
        int o = excl + loc[j];
        offsets[base + j] = o;
        cursor[base + j]  = o;
    }
    if (tid == 255) offsets[KC] = excl + s;
    for (int m = 128; m > 0; m >>= 1) {
        if (tid < m) fpart[tid] += fpart[tid + m];
        __syncthreads();
    }
    if (tid == 0) n_out[0] = fpart[0];
}

// ---------------- kernel: scatter row indices into code-sorted order ----------------
__global__ void k_scatteridx(const int* __restrict__ codes_i,
                             int* __restrict__ cursor, int* __restrict__ sorted_rows) {
    int r = blockIdx.x * 256 + threadIdx.x;
    if (r < NROWS) {
        int c = codes_i[r];
        int p = atomicAdd(&cursor[c], 1);
        sorted_rows[p] = r;
    }
}

// ---------------- kernel: segmented sum -> dw, fused EMA-w + new embedding ----------------
__global__ __launch_bounds__(64) void k_dwsum(
        const float* __restrict__ z, const int* __restrict__ offsets,
        const int* __restrict__ sorted_rows, const float* __restrict__ ema_w,
        const float* __restrict__ ncs, const float* __restrict__ nptr,
        float* __restrict__ new_ema_w_out, float* __restrict__ new_emb_out) {
    int k = blockIdx.x, tid = threadIdx.x;
    int beg = offsets[k], end = offsets[k + 1];
    float a0 = 0.f, a1 = 0.f, a2 = 0.f, a3 = 0.f;
    int i = beg;
    for (; i + 3 < end; i += 4) {
        int r0 = sorted_rows[i], r1 = sorted_rows[i + 1];
        int r2 = sorted_rows[i + 2], r3 = sorted_rows[i + 3];
        a0 += z[(size_t)r0 * DIM + tid];
        a1 += z[(size_t)r1 * DIM + tid];
        a2 += z[(size_t)r2 * DIM + tid];
        a3 += z[(size_t)r3 * DIM + tid];
    }
    for (; i < end; ++i) a0 += z[(size_t)sorted_rows[i] * DIM + tid];
    float dwv = (a0 + a1) + (a2 + a3);
    size_t idx = (size_t)k * DIM + tid;
    float n = nptr[0];
    float nw = 0.99f * ema_w[idx] + 0.01f * dwv;
    float cs = (ncs[k] + 1e-5f) / (n + 4096.0f * 1e-5f) * n;
    new_ema_w_out[idx] = nw;
    new_emb_out[idx] = nw / cs;
}

// ---------------- kernel: quantize + straight-through + loss ----------------
__global__ __launch_bounds__(256) void k_quant(
        const float* __restrict__ z, const float* __restrict__ new_emb,
        const int* __restrict__ codes, float* __restrict__ zq_out,
        double* __restrict__ loss_acc) {
    __shared__ double red[256];
    const int nvec = NELEM / 4;
    int t = blockIdx.x * 256 + threadIdx.x;
    int stride = gridDim.x * 256;
    double ls = 0.0;
    for (int v = t; v < nvec; v += stride) {
        int e0 = v * 4;
        int n  = e0 >> 6;
        int d0 = e0 & 63;
        int code = codes[n];
        float4 zq = *(const float4*)&new_emb[(size_t)code * DIM + d0];
        float4 zv = *(const float4*)&z[e0];
        float dx = zq.x - zv.x, dy = zq.y - zv.y, dz = zq.z - zv.z, dw4 = zq.w - zv.w;
        float4 o;
        o.x = zv.x + dx; o.y = zv.y + dy; o.z = zv.z + dz; o.w = zv.w + dw4;
        *(float4*)&zq_out[e0] = o;
        ls += (double)(dx * dx) + (double)(dy * dy) + (double)(dz * dz) + (double)(dw4 * dw4);
    }
    red[threadIdx.x] = ls;
    __syncthreads();
    for (int m = 128; m > 0; m >>= 1) {
        if (threadIdx.x < m) red[threadIdx.x] += red[threadIdx.x + m];
        __syncthreads();
    }
    if (threadIdx.x == 0) atomicAdd(loss_acc, red[0]);
}

__global__ void k_loss(const double* __restrict__ loss_acc, float* __restrict__ out0) {
    out0[0] = (float)(0.25 * (loss_acc[0] / (double)NELEM));
}

// ---------------- launcher ----------------
extern "C" void kernel_launch(void* const* d_in, const int* in_sizes, int n_in,
                              void* d_out, int out_size, void* d_ws, size_t ws_size,
                              hipStream_t stream) {
    const float* z      = (const float*)d_in[0];
    const float* emb    = (const float*)d_in[1];
    const float* ema_cs = (const float*)d_in[2];
    const float* ema_w  = (const float*)d_in[3];
    float* out = (float*)d_out;
    char*  ws  = (char*)d_ws;

    int*    codes_i = (int*)(ws + WS_CODES);
    int*    counts  = (int*)(ws + WS_COUNTS);
    int*    offsets = (int*)(ws + WS_OFFS);
    int*    cursor  = (int*)(ws + WS_CURSOR);
    int*    sorted  = (int*)(ws + WS_SORTED);
    float*  nptr    = (float*)(ws + WS_N);
    double* lossp   = (double*)(ws + WS_LOSSD);
    char*   emb_pk  = ws + WS_EMBPK;
    float*  dw      = nullptr;  // dw now folded into k_dwsum epilogue (no buffer)

    (void)dw;
    k_prep<<<(KC * 8) / 256, 256, 0, stream>>>(emb, emb_pk, counts);
    k_argmin6<<<NROWS / 96, 192, 0, stream>>>(z, emb_pk, codes_i,
                                              out + OUT_CODES, counts);
    k_scan<<<1, 256, 0, stream>>>(counts, offsets, cursor, ema_cs,
                                  out + OUT_NCS, nptr, lossp);
    k_scatteridx<<<(NROWS + 255) / 256, 256, 0, stream>>>(codes_i, cursor, sorted);
    k_dwsum<<<KC, 64, 0, stream>>>(z, offsets, sorted, ema_w,
                                   out + OUT_NCS, nptr, out + OUT_NEW, out + OUT_EMB);
    k_quant<<<1152, 256, 0, stream>>>(z, out + OUT_EMB, codes_i,
                                      out + OUT_ZQ, lossp);
    k_loss<<<1, 1, 0, stream>>>(lossp, out + OUT_LOSS);
}

// Round 8
// 167.582 us; speedup vs baseline: 4.0572x; 1.0762x over previous
//
#include <hip/hip_runtime.h>

// ---------------- problem constants ----------------
constexpr int KC    = 4096;      // NUM_EMBEDDINGS
constexpr int DIM   = 64;        // EMBEDDING_DIM
constexpr int NROWS = 73728;     // 128*24*1536/64
constexpr int NELEM = 4718592;   // 128*24*1536
constexpr int GSTRIDE = 4160;    // per-16-code group block: 64B e2s + 4KB frags

typedef _Float16 f16x8 __attribute__((ext_vector_type(8)));
typedef float    f32x4 __attribute__((ext_vector_type(4)));

// ---------------- output layout (floats) ----------------
constexpr size_t OUT_LOSS  = 0;                               // 1
constexpr size_t OUT_ZQ    = 1;                               // NELEM
constexpr size_t OUT_CODES = 1 + (size_t)NELEM;               // NROWS
constexpr size_t OUT_EMB   = OUT_CODES + (size_t)NROWS;       // KC*DIM
constexpr size_t OUT_NCS   = OUT_EMB + (size_t)KC * DIM;      // KC
constexpr size_t OUT_NEW   = OUT_NCS + (size_t)KC;            // KC*DIM

// ---------------- workspace layout (bytes) ----------------
constexpr size_t alignup(size_t x, size_t a) { return (x + a - 1) & ~(a - 1); }
constexpr size_t WS_CODES  = 0;                                            // int[NROWS]
constexpr size_t WS_COUNTS = WS_CODES + sizeof(int) * (size_t)NROWS;       // int[KC]
constexpr size_t WS_OFFS   = WS_COUNTS + sizeof(int) * (size_t)KC;         // int[KC+1]
constexpr size_t WS_CURSOR = alignup(WS_OFFS + sizeof(int) * (KC + 1), 16);// int[KC]
constexpr size_t WS_SORTED = WS_CURSOR + sizeof(int) * (size_t)KC;         // int[NROWS]
constexpr size_t WS_N      = alignup(WS_SORTED + sizeof(int) * (size_t)NROWS, 16); // float[1]
constexpr size_t WS_LOSSD  = alignup(WS_N + sizeof(float), 8);             // double[1]
constexpr size_t WS_EMBPK  = alignup(WS_LOSSD + 8, 64);                    // 260*4160 (incl dummy tail)

// ---------------- kernel: pack emb -> group blocks {e2s[16], hi/lo frags} + zero counts ----
// group g at g*4160: [0,64) = e2s floats (2^11 * 0.5*||e||^2 for the 16 codes);
// [64,4160) = frag f (0:hi-h0,1:hi-h1,2:lo-h0,3:lo-h1) at 64+f*1024, lane l at +l*16:
// e[g*16+(l&15)][h*32 + (l>>4)*8 .. +8].
__global__ void k_prep(const float* __restrict__ emb, char* __restrict__ emb_pk,
                       int* __restrict__ counts) {
    if (threadIdx.x < 32) counts[blockIdx.x * 32 + threadIdx.x] = 0;
    int t = blockIdx.x * 256 + threadIdx.x;   // 0 .. 32767
    int c = t >> 3, q = t & 7;                // code, d-chunk of 8
    const float* ep = emb + (size_t)c * DIM + q * 8;
    f16x8 hv, lv;
    float s = 0.f;
    #pragma unroll
    for (int e = 0; e < 8; ++e) {
        float x = ep[e];
        _Float16 h = (_Float16)x;
        float r = x - (float)h;
        hv[e] = h;                          // raw e_hi
        lv[e] = (_Float16)(r * 2048.0f);    // 2^11 * e_lo
        s = fmaf(x, x, s);
    }
    s += __shfl_xor(s, 1, 64);
    s += __shfl_xor(s, 2, 64);
    s += __shfl_xor(s, 4, 64);
    int g = c >> 4, lc = c & 15;
    int h = q >> 2, lq = q & 3;
    int lane = lq * 16 + lc;
    char* gbase = emb_pk + (size_t)g * GSTRIDE;
    if (q == 0) *(float*)(gbase + lc * 4) = 1024.0f * s;   // 2^11*(0.5*sum e^2)
    char* base = gbase + 64 + lane * 16;
    *(f16x8*)(base + h * 1024)       = hv;
    *(f16x8*)(base + (2 + h) * 1024) = lv;
}

// ---------------- kernel: MFMA distance argmin, 48 rows/wave, counted-vmcnt pipeline ----
// 512 blocks x 192 threads (3 waves) = exactly 2 blocks/CU, 6 waves/CU. Wave owns
// 48 rows (3 x 16-row fragments -> 3 independent 6-MFMA chains/group = 18 MFMAs),
// sweeps all 256 groups; 4 asm-pinned load stages (20 loads in flight), vmcnt(15)
// per group. No __syncthreads. dist' = 2^11*(0.5||e||^2 - z.e).
__global__ __launch_bounds__(192, 2) void k_argmin7(
        const float* __restrict__ z, const char* __restrict__ emb_pk,
        int* __restrict__ codes_i, float* __restrict__ codes_f,
        int* __restrict__ counts) {
    __shared__ int codebuf[3][48];

    const int tid = threadIdx.x;
    const int l   = tid & 63;
    const int w   = tid >> 6;
    const int lc  = l & 15;
    const int lq  = l >> 4;
    const int waveRow = blockIdx.x * 144 + w * 48;

    // ---- A fragments: 48 z-rows -> three negated scaled fp16 forms ----
    f16x8 ah2k[3][2], ahr[3][2], al2k[3][2];
    #pragma unroll
    for (int rt = 0; rt < 3; ++rt)
        #pragma unroll
        for (int h = 0; h < 2; ++h) {
            const float* zp = z + (size_t)(waveRow + rt * 16 + lc) * DIM + h * 32 + lq * 8;
            float4 x0 = *(const float4*)zp;
            float4 x1 = *(const float4*)(zp + 4);
            float xs[8] = {x0.x, x0.y, x0.z, x0.w, x1.x, x1.y, x1.z, x1.w};
            #pragma unroll
            for (int e = 0; e < 8; ++e) {
                _Float16 hh = (_Float16)xs[e];
                float rr = xs[e] - (float)hh;
                ahr[rt][h][e]  = -hh;
                ah2k[rt][h][e] = (_Float16)(-2048.0f * (float)hh);   // exact pow2 scale
                al2k[rt][h][e] = -(_Float16)(rr * 2048.0f);
            }
        }

    float best[3][4];
    int   bestg[3][4];
    #pragma unroll
    for (int rt = 0; rt < 3; ++rt)
        #pragma unroll
        for (int j = 0; j < 4; ++j) { best[rt][j] = INFINITY; bestg[rt][j] = 0; }

    const unsigned long long pkb = (unsigned long long)emb_pk;
    unsigned voffA = 64 + l * 16;   // fragment stream
    unsigned voffB = lc * 4;        // e2s stream

    f16x8 b00, b01, b02, b03, b10, b11, b12, b13;
    f16x8 b20, b21, b22, b23, b30, b31, b32, b33;
    float e0, e1, e2v, e3;

#define ISSUE(B0, B1, B2, B3, EV)                                                        \
    asm volatile("global_load_dword %0, %1, %2"             : "=v"(EV) : "v"(voffB), "s"(pkb)); \
    asm volatile("global_load_dwordx4 %0, %1, %2"             : "=v"(B0) : "v"(voffA), "s"(pkb)); \
    asm volatile("global_load_dwordx4 %0, %1, %2 offset:1024" : "=v"(B1) : "v"(voffA), "s"(pkb)); \
    asm volatile("global_load_dwordx4 %0, %1, %2 offset:2048" : "=v"(B2) : "v"(voffA), "s"(pkb)); \
    asm volatile("global_load_dwordx4 %0, %1, %2 offset:3072" : "=v"(B3) : "v"(voffA), "s"(pkb)); \
    voffA += GSTRIDE; voffB += GSTRIDE;

#define WAITP                                                \
    asm volatile("s_waitcnt vmcnt(15)" ::: "memory");        \
    __builtin_amdgcn_sched_barrier(0);

#define COMP(B0, B1, B2, B3, EV, G) {                                             \
        f32x4 ci; ci[0] = EV; ci[1] = EV; ci[2] = EV; ci[3] = EV;                 \
        _Pragma("unroll")                                                         \
        for (int rt = 0; rt < 3; ++rt) {                                          \
            f32x4 acc = __builtin_amdgcn_mfma_f32_16x16x32_f16(ah2k[rt][0], B0, ci, 0, 0, 0); \
            acc = __builtin_amdgcn_mfma_f32_16x16x32_f16(ah2k[rt][1], B1, acc, 0, 0, 0);      \
            acc = __builtin_amdgcn_mfma_f32_16x16x32_f16(ahr[rt][0],  B2, acc, 0, 0, 0);      \
            acc = __builtin_amdgcn_mfma_f32_16x16x32_f16(ahr[rt][1],  B3, acc, 0, 0, 0);      \
            acc = __builtin_amdgcn_mfma_f32_16x16x32_f16(al2k[rt][0], B0, acc, 0, 0, 0);      \
            acc = __builtin_amdgcn_mfma_f32_16x16x32_f16(al2k[rt][1], B1, acc, 0, 0, 0);      \
            _Pragma("unroll")                                                     \
            for (int j = 0; j < 4; ++j) {                                         \
                if (acc[j] < best[rt][j]) { best[rt][j] = acc[j]; bestg[rt][j] = (G); } \
            }                                                                     \
        } }

    __builtin_amdgcn_sched_barrier(0);   // keep A-prep (and its waits) above the asm stream
    ISSUE(b00, b01, b02, b03, e0)        // G0
    ISSUE(b10, b11, b12, b13, e1)        // G1
    ISSUE(b20, b21, b22, b23, e2v)       // G2
    ISSUE(b30, b31, b32, b33, e3)        // G3

    for (int g = 0; g < 256; g += 4) {
        WAITP  COMP(b00, b01, b02, b03, e0,  g)      ISSUE(b00, b01, b02, b03, e0)
        WAITP  COMP(b10, b11, b12, b13, e1,  g + 1)  ISSUE(b10, b11, b12, b13, e1)
        WAITP  COMP(b20, b21, b22, b23, e2v, g + 2)  ISSUE(b20, b21, b22, b23, e2v)
        WAITP  COMP(b30, b31, b32, b33, e3,  g + 3)  ISSUE(b30, b31, b32, b33, e3)
    }
    asm volatile("s_waitcnt vmcnt(0)" ::: "memory");   // drain dummy tail loads
    __builtin_amdgcn_sched_barrier(0);
#undef ISSUE
#undef WAITP
#undef COMP

    // ---- butterfly argmin reduce over the 16 lanes of each lq-group ----
    #pragma unroll
    for (int rt = 0; rt < 3; ++rt)
        #pragma unroll
        for (int j = 0; j < 4; ++j) {
            float b = best[rt][j];
            int   k = bestg[rt][j] * 16 + lc;
            #pragma unroll
            for (int m = 1; m < 16; m <<= 1) {
                float obv = __shfl_xor(b, m, 64);
                int   okv = __shfl_xor(k, m, 64);
                if (obv < b || (obv == b && okv < k)) { b = obv; k = okv; }
            }
            if (lc == 0) codebuf[w][rt * 16 + lq * 4 + j] = k;   // D row = lq*4+j
        }

    // ---- emit codes + int counts (within-wave LDS dep only; no barrier) ----
    if (l < 48) {
        int code = codebuf[w][l];
        size_t rowg = (size_t)waveRow + l;
        codes_i[rowg] = code;
        codes_f[rowg] = (float)code;
        atomicAdd(&counts[code], 1);
    }
}

// ---------------- kernel: scan counts -> offsets/cursor + cluster-size + n + loss=0 ----
__global__ void k_scan(const int* __restrict__ counts,
                       int* __restrict__ offsets, int* __restrict__ cursor,
                       const float* __restrict__ ema_cs, float* __restrict__ ncs_out,
                       float* __restrict__ n_out, double* __restrict__ lossp) {
    __shared__ int   part[256];
    __shared__ float fpart[256];
    int tid = threadIdx.x;
    if (tid == 0) *lossp = 0.0;
    int base = tid * 16;
    int loc[16];
    int s = 0;
    float fs = 0.f;
    #pragma unroll
    for (int j = 0; j < 16; ++j) {
        int cnt = counts[base + j];
        loc[j] = s; s += cnt;
        float v = 0.99f * ema_cs[base + j] + 0.01f * (float)cnt;
        ncs_out[base + j] = v;
        fs += v;
    }
    part[tid] = s;
    fpart[tid] = fs;
    __syncthreads();
    for (int off = 1; off < 256; off <<= 1) {
        int v = (tid >= off) ? part[tid - off] : 0;
        __syncthreads();
        part[tid] += v;
        __syncthreads();
    }
    int excl = part[tid] - s;
    #pragma unroll
    for (int j = 0; j < 16; ++j) {
        int o = excl + loc[j];
        offsets[base + j] = o;
        cursor[base + j]  = o;
    }
    if (tid == 255) offsets[KC] = excl + s;
    for (int m = 128; m > 0; m >>= 1) {
        if (tid < m) fpart[tid] += fpart[tid + m];
        __syncthreads();
    }
    if (tid == 0) n_out[0] = fpart[0];
}

// ---------------- kernel: scatter row indices into code-sorted order ----------------
__global__ void k_scatteridx(const int* __restrict__ codes_i,
                             int* __restrict__ cursor, int* __restrict__ sorted_rows) {
    int r = blockIdx.x * 256 + threadIdx.x;
    if (r < NROWS) {
        int c = codes_i[r];
        int p = atomicAdd(&cursor[c], 1);
        sorted_rows[p] = r;
    }
}

// ---------------- kernel: segmented sum -> dw, fused EMA-w + new embedding ----------------
__global__ __launch_bounds__(64) void k_dwsum(
        const float* __restrict__ z, const int* __restrict__ offsets,
        const int* __restrict__ sorted_rows, const float* __restrict__ ema_w,
        const float* __restrict__ ncs, const float* __restrict__ nptr,
        float* __restrict__ new_ema_w_out, float* __restrict__ new_emb_out) {
    int k = blockIdx.x, tid = threadIdx.x;
    int beg = offsets[k], end = offsets[k + 1];
    float a0 = 0.f, a1 = 0.f, a2 = 0.f, a3 = 0.f;
    int i = beg;
    for (; i + 3 < end; i += 4) {
        int r0 = sorted_rows[i], r1 = sorted_rows[i + 1];
        int r2 = sorted_rows[i + 2], r3 = sorted_rows[i + 3];
        a0 += z[(size_t)r0 * DIM + tid];
        a1 += z[(size_t)r1 * DIM + tid];
        a2 += z[(size_t)r2 * DIM + tid];
        a3 += z[(size_t)r3 * DIM + tid];
    }
    for (; i < end; ++i) a0 += z[(size_t)sorted_rows[i] * DIM + tid];
    float dwv = (a0 + a1) + (a2 + a3);
    size_t idx = (size_t)k * DIM + tid;
    float n = nptr[0];
    float nw = 0.99f * ema_w[idx] + 0.01f * dwv;
    float cs = (ncs[k] + 1e-5f) / (n + 4096.0f * 1e-5f) * n;
    new_ema_w_out[idx] = nw;
    new_emb_out[idx] = nw / cs;
}

// ---------------- kernel: quantize + straight-through + loss ----------------
__global__ __launch_bounds__(256) void k_quant(
        const float* __restrict__ z, const float* __restrict__ new_emb,
        const int* __restrict__ codes, float* __restrict__ zq_out,
        double* __restrict__ loss_acc) {
    __shared__ double red[256];
    const int nvec = NELEM / 4;
    int t = blockIdx.x * 256 + threadIdx.x;
    int stride = gridDim.x * 256;
    double ls = 0.0;
    for (int v = t; v < nvec; v += stride) {
        int e0 = v * 4;
        int n  = e0 >> 6;
        int d0 = e0 & 63;
        int code = codes[n];
        float4 zq = *(const float4*)&new_emb[(size_t)code * DIM + d0];
        float4 zv = *(const float4*)&z[e0];
        float dx = zq.x - zv.x, dy = zq.y - zv.y, dz = zq.z - zv.z, dw4 = zq.w - zv.w;
        float4 o;
        o.x = zv.x + dx; o.y = zv.y + dy; o.z = zv.z + dz; o.w = zv.w + dw4;
        *(float4*)&zq_out[e0] = o;
        ls += (double)(dx * dx) + (double)(dy * dy) + (double)(dz * dz) + (double)(dw4 * dw4);
    }
    red[threadIdx.x] = ls;
    __syncthreads();
    for (int m = 128; m > 0; m >>= 1) {
        if (threadIdx.x < m) red[threadIdx.x] += red[threadIdx.x + m];
        __syncthreads();
    }
    if (threadIdx.x == 0) atomicAdd(loss_acc, red[0]);
}

__global__ void k_loss(const double* __restrict__ loss_acc, float* __restrict__ out0) {
    out0[0] = (float)(0.25 * (loss_acc[0] / (double)NELEM));
}

// ---------------- launcher ----------------
extern "C" void kernel_launch(void* const* d_in, const int* in_sizes, int n_in,
                              void* d_out, int out_size, void* d_ws, size_t ws_size,
                              hipStream_t stream) {
    const float* z      = (const float*)d_in[0];
    const float* emb    = (const float*)d_in[1];
    const float* ema_cs = (const float*)d_in[2];
    const float* ema_w  = (const float*)d_in[3];
    float* out = (float*)d_out;
    char*  ws  = (char*)d_ws;

    int*    codes_i = (int*)(ws + WS_CODES);
    int*    counts  = (int*)(ws + WS_COUNTS);
    int*    offsets = (int*)(ws + WS_OFFS);
    int*    cursor  = (int*)(ws + WS_CURSOR);
    int*    sorted  = (int*)(ws + WS_SORTED);
    float*  nptr    = (float*)(ws + WS_N);
    double* lossp   = (double*)(ws + WS_LOSSD);
    char*   emb_pk  = ws + WS_EMBPK;

    k_prep<<<(KC * 8) / 256, 256, 0, stream>>>(emb, emb_pk, counts);
    k_argmin7<<<NROWS / 144, 192, 0, stream>>>(z, emb_pk, codes_i,
                                               out + OUT_CODES, counts);
    k_scan<<<1, 256, 0, stream>>>(counts, offsets, cursor, ema_cs,
                                  out + OUT_NCS, nptr, lossp);
    k_scatteridx<<<(NROWS + 255) / 256, 256, 0, stream>>>(codes_i, cursor, sorted);
    k_dwsum<<<KC, 64, 0, stream>>>(z, offsets, sorted, ema_w,
                                   out + OUT_NCS, nptr, out + OUT_NEW, out + OUT_EMB);
    k_quant<<<1152, 256, 0, stream>>>(z, out + OUT_EMB, codes_i,
                                      out + OUT_ZQ, lossp);
    k_loss<<<1, 1, 0, stream>>>(lossp, out + OUT_LOSS);
}